// Round 1
// baseline (699.955 us; speedup 1.0000x reference)
//
#include <hip/hip_runtime.h>
#include <math.h>

#define F_MH 4
#define NB   512
#define SEQ  2048
#define TOPK 128
#define EDIM 64
#define ADIM 128
#define VOH  10001
#define VMH  100001
#define NROWS (F_MH * VMH)   // 400004
#define D0   1728
#define RSQRT32 0.17677669529663687f

// ---------------------------------------------------------------------------
// K1: per-vocab-row packed LSH signatures. [rows x 64] @ [64 x 32] -> sign bits
// 128 rows per block, thread = 4 rows x 4 bits micro-tile, b128 LDS reads.
// ---------------------------------------------------------------------------
__global__ __launch_bounds__(256) void k_hash(const float* __restrict__ tab,
                                              const float* __restrict__ hw,
                                              unsigned int* __restrict__ sig)
{
    __shared__ float WT[32][68];     // WT[h][e] = hw[e*32+h], padded
    __shared__ float embs[128][68];  // padded rows
    __shared__ unsigned int sigl[128];
    const int t = threadIdx.x;
    for (int i = t; i < 2048; i += 256) WT[i & 31][i >> 5] = hw[i];
    if (t < 128) sigl[t] = 0u;
    const int base = blockIdx.x * 128;
    const float4* src = (const float4*)(tab + (size_t)base * 64);
    const int lim4 = (NROWS - base) * 16;
#pragma unroll
    for (int i = 0; i < 8; ++i) {
        int v = t + i * 256;
        float4 ev = make_float4(0.f, 0.f, 0.f, 0.f);
        if (v < lim4) ev = src[v];
        *(float4*)&embs[v >> 4][(v & 15) << 2] = ev;
    }
    __syncthreads();
    const int rq = t >> 3, hq = t & 7;
    float acc[4][4];
#pragma unroll
    for (int i = 0; i < 4; ++i)
#pragma unroll
        for (int j = 0; j < 4; ++j) acc[i][j] = 0.f;
#pragma unroll
    for (int e4 = 0; e4 < 16; ++e4) {
        float4 a[4], w[4];
#pragma unroll
        for (int i = 0; i < 4; ++i) a[i] = *(const float4*)&embs[rq * 4 + i][e4 * 4];
#pragma unroll
        for (int j = 0; j < 4; ++j) w[j] = *(const float4*)&WT[hq * 4 + j][e4 * 4];
#pragma unroll
        for (int i = 0; i < 4; ++i)
#pragma unroll
            for (int j = 0; j < 4; ++j)
                acc[i][j] += a[i].x * w[j].x + a[i].y * w[j].y + a[i].z * w[j].z + a[i].w * w[j].w;
    }
#pragma unroll
    for (int i = 0; i < 4; ++i) {
        unsigned int bits = 0u;
#pragma unroll
        for (int j = 0; j < 4; ++j)
            if (acc[i][j] > 0.f) bits |= (1u << (hq * 4 + j));
        if (bits) atomicOr(&sigl[rq * 4 + i], bits);
    }
    __syncthreads();
    if (t < 128 && base + t < NROWS) sig[base + t] = sigl[t];
}

// ---------------------------------------------------------------------------
// K2: per-(f,b) top-K=128 by Hamming distance. Histogram over d in [0,33],
// threshold D*, stable (lowest-s-first) tie selection == jax.lax.top_k set.
// Stores the selected VOCAB ids directly.
// ---------------------------------------------------------------------------
__global__ __launch_bounds__(256) void k_topk(const float* __restrict__ oh_tab,
                                              const float* __restrict__ hw,
                                              const unsigned int* __restrict__ sig,
                                              const int* __restrict__ oh_ids,
                                              const int* __restrict__ mh_ids,
                                              int* __restrict__ sel)
{
    const int b = blockIdx.x, f = blockIdx.y, t = threadIdx.x;
    __shared__ float tgt[64];
    __shared__ unsigned int thbits;
    __shared__ int hist[34];
    __shared__ int c_lt[256], c_eq[256];
    __shared__ int s_dstar, s_cntlt;
    if (t < 64) tgt[t] = oh_tab[((size_t)f * VOH + oh_ids[b * 15 + f]) * 64 + t];
    if (t == 0) thbits = 0u;
    if (t < 34) hist[t] = 0;
    __syncthreads();
    if (t < 32) {
        float acc = 0.f;
#pragma unroll
        for (int e = 0; e < 64; ++e) acc += tgt[e] * hw[e * 32 + t];
        if (acc > 0.f) atomicOr(&thbits, 1u << t);
    }
    __syncthreads();
    const unsigned int th = thbits;
    const int* idp = mh_ids + (size_t)(f * NB + b) * SEQ + t * 8;
    int ids[8], dv[8];
#pragma unroll
    for (int j = 0; j < 8; ++j) {
        int id = idp[j];
        ids[j] = id;
        int d = (id >= 0) ? __popc(sig[f * VMH + id] ^ th) : 33;
        dv[j] = d;
        atomicAdd(&hist[d], 1);
    }
    __syncthreads();
    if (t == 0) {
        int cum = 0, ds = 33, cl = 0;
        for (int d = 0; d <= 33; ++d) {
            if (cum + hist[d] >= TOPK) { ds = d; cl = cum; break; }
            cum += hist[d];
        }
        s_dstar = ds; s_cntlt = cl;
    }
    __syncthreads();
    const int Dstar = s_dstar, cntlt = s_cntlt;
    int nlt = 0, neq = 0;
#pragma unroll
    for (int j = 0; j < 8; ++j) {
        nlt += (dv[j] < Dstar);
        neq += (dv[j] == Dstar);
    }
    c_lt[t] = nlt; c_eq[t] = neq;
    __syncthreads();
    for (int off = 1; off < 256; off <<= 1) {   // inclusive Hillis-Steele scan
        int vl = 0, ve = 0;
        if (t >= off) { vl = c_lt[t - off]; ve = c_eq[t - off]; }
        __syncthreads();
        c_lt[t] += vl; c_eq[t] += ve;
        __syncthreads();
    }
    int lt_pos = c_lt[t] - nlt;
    int eq_pos = cntlt + c_eq[t] - neq;
    int* selp = sel + (size_t)(f * NB + b) * TOPK;
#pragma unroll
    for (int j = 0; j < 8; ++j) {
        if (dv[j] < Dstar) { selp[lt_pos++] = ids[j]; }
        else if (dv[j] == Dstar) {
            if (eq_pos < TOPK) selp[eq_pos] = ids[j];
            eq_pos++;
        }
    }
}

// ---------------------------------------------------------------------------
// K3: single-query attention (short z=0 / long z=1) with q folded into kW and
// attention weights folded into the embedding (no K/V materialization).
// Writes its 64-float result straight into the feats buffer.
// ---------------------------------------------------------------------------
__global__ __launch_bounds__(256) void k_attn(const float* __restrict__ oh_tab,
                                              const float* __restrict__ mh_tab,
                                              const int* __restrict__ oh_ids,
                                              const int* __restrict__ mh_ids,
                                              const int* __restrict__ sel,
                                              const float* __restrict__ sqW, const float* __restrict__ sqb,
                                              const float* __restrict__ skW, const float* __restrict__ skb,
                                              const float* __restrict__ svW, const float* __restrict__ svb,
                                              const float* __restrict__ soW, const float* __restrict__ sob,
                                              const float* __restrict__ lqW, const float* __restrict__ lqb,
                                              const float* __restrict__ lkW, const float* __restrict__ lkb,
                                              const float* __restrict__ lvW, const float* __restrict__ lvb,
                                              const float* __restrict__ loW, const float* __restrict__ lob,
                                              float* __restrict__ feats)
{
    const int b = blockIdx.x, f = blockIdx.y, z = blockIdx.z, t = threadIdx.x;
    const float* WQ = (z ? lqW : sqW) + (size_t)f * (EDIM * ADIM);
    const float* bq = (z ? lqb : sqb) + f * ADIM;
    const float* WK = (z ? lkW : skW) + (size_t)f * (EDIM * ADIM);
    const float* bk = (z ? lkb : skb) + f * ADIM;
    const float* WV = (z ? lvW : svW) + (size_t)f * (EDIM * ADIM);
    const float* bv = (z ? lvb : svb) + f * ADIM;
    const float* WO = (z ? loW : soW) + (size_t)f * (ADIM * 64);
    const float* bo = (z ? lob : sob) + f * 64;

    __shared__ float tgt[64];
    __shared__ int   sid[128];
    __shared__ float seqT[64][132];   // seqT[e][s], padded (132%4==0)
    __shared__ float qv[128];
    __shared__ float qk[4][64];
    __shared__ float qkb4[4];
    __shared__ float sc[4][128];      // scores, then attn weights in place
    __shared__ float wemb[4][64];
    __shared__ float outv[128];

    if (t < 64) tgt[t] = oh_tab[((size_t)f * VOH + oh_ids[b * 15 + f]) * 64 + t];
    if (t < 128) {
        int id;
        if (z == 0) id = mh_ids[(size_t)(f * NB + b) * SEQ + t];
        else        id = sel[(size_t)(f * NB + b) * TOPK + t];
        sid[t] = id;
    }
    __syncthreads();
    // stage gathered embeddings (transposed)
#pragma unroll
    for (int i = 0; i < 8; ++i) {
        int v = t + i * 256;
        int row = v >> 4, c4 = (v & 15) << 2;
        int id = sid[row];
        float4 ev = make_float4(0.f, 0.f, 0.f, 0.f);
        if (id >= 0) ev = *(const float4*)&mh_tab[((size_t)f * VMH + id) * 64 + c4];
        seqT[c4 + 0][row] = ev.x; seqT[c4 + 1][row] = ev.y;
        seqT[c4 + 2][row] = ev.z; seqT[c4 + 3][row] = ev.w;
    }
    // q projection (1 x 128)
    if (t < 128) {
        float acc = bq[t];
#pragma unroll
        for (int e = 0; e < 64; ++e) acc += tgt[e] * WQ[e * 128 + t];
        qv[t] = acc;
    }
    __syncthreads();
    // fold q into kW: qk[h][e] = (1/sqrt(32)) * sum_d q[h*32+d] * kW[e][h*32+d]
    {
        const int h = t >> 6, e = t & 63;
        float acc = 0.f;
#pragma unroll
        for (int d = 0; d < 32; ++d) acc += qv[h * 32 + d] * WK[e * 128 + h * 32 + d];
        qk[h][e] = acc * RSQRT32;
    }
    if (t < 4) {
        float acc = 0.f;
#pragma unroll
        for (int d = 0; d < 32; ++d) acc += qv[t * 32 + d] * bk[t * 32 + d];
        qkb4[t] = acc * RSQRT32;
    }
    __syncthreads();
    // scores[h][s]
#pragma unroll
    for (int rep = 0; rep < 2; ++rep) {
        int idx = t + rep * 256;
        int h = idx >> 7, s = idx & 127;
        float acc = qkb4[h];
#pragma unroll
        for (int e4 = 0; e4 < 16; ++e4) {
            float4 q4 = *(const float4*)&qk[h][e4 * 4];
            acc += seqT[e4 * 4 + 0][s] * q4.x + seqT[e4 * 4 + 1][s] * q4.y
                 + seqT[e4 * 4 + 2][s] * q4.z + seqT[e4 * 4 + 3][s] * q4.w;
        }
        sc[h][s] = (sid[s] >= 0) ? acc : -INFINITY;
    }
    __syncthreads();
    // softmax: wave w handles head h=w, lanes cover s and s+64
    {
        const int h = t >> 6, l = t & 63;
        float v0 = sc[h][l], v1 = sc[h][l + 64];
        float m = fmaxf(v0, v1);
        for (int off = 32; off; off >>= 1) m = fmaxf(m, __shfl_xor(m, off));
        float p0 = expf(v0 - m), p1 = expf(v1 - m);
        float ssum = p0 + p1;
        for (int off = 32; off; off >>= 1) ssum += __shfl_xor(ssum, off);
        float inv = 1.f / ssum;
        sc[h][l] = p0 * inv; sc[h][l + 64] = p1 * inv;
    }
    __syncthreads();
    // wemb[h][e] = sum_s attn[h][s] * seq[s][e]
    {
        const int h = t >> 6, e = t & 63;
        float acc = 0.f;
#pragma unroll
        for (int s4 = 0; s4 < 32; ++s4) {
            float4 a4 = *(const float4*)&sc[h][s4 * 4];
            float4 e4 = *(const float4*)&seqT[e][s4 * 4];
            acc += a4.x * e4.x + a4.y * e4.y + a4.z * e4.z + a4.w * e4.w;
        }
        wemb[h][e] = acc;
    }
    __syncthreads();
    // out[a] = wemb[h(a)] . vW[:,a] + vb[a]
    if (t < 128) {
        const int h = t >> 5;
        float acc = bv[t];
#pragma unroll
        for (int e = 0; e < 64; ++e) acc += wemb[h][e] * WV[e * 128 + t];
        outv[t] = acc;
    }
    __syncthreads();
    // final[o] = out . oW[:,o] + ob[o] -> feats
    if (t < 64) {
        float acc = bo[t];
#pragma unroll
        for (int a = 0; a < 128; ++a) acc += outv[a] * WO[a * 64 + t];
        feats[(size_t)b * D0 + (z ? 1472 : 1216) + f * 64 + t] = acc;
    }
}

// ---------------------------------------------------------------------------
// K4: feats assembly: one-hot gathers (960) + special sum-pooled (256)
// ---------------------------------------------------------------------------
__global__ __launch_bounds__(256) void k_feats(const float* __restrict__ oh_tab,
                                               const float* __restrict__ sp_tab,
                                               const int* __restrict__ oh_ids,
                                               const int* __restrict__ sp_ids,
                                               float* __restrict__ feats)
{
    const int b = blockIdx.x, t = threadIdx.x;
    __shared__ int sidl[200];
    __shared__ int ohid[15];
    if (t < 200) sidl[t] = sp_ids[(size_t)((t / 50) * NB + b) * 50 + (t % 50)];
    if (t >= 240 && t < 255) ohid[t - 240] = oh_ids[b * 15 + (t - 240)];
    __syncthreads();
    float* fr = feats + (size_t)b * D0;
    for (int p = t; p < 960; p += 256) {
        int f = p >> 6, e = p & 63;
        fr[p] = oh_tab[((size_t)f * VOH + ohid[f]) * 64 + e];
    }
    {
        int f = t >> 6, e = t & 63;
        float acc = 0.f;
        for (int j = 0; j < 50; ++j) {
            int id = sidl[f * 50 + j];
            if (id >= 0) acc += sp_tab[((size_t)f * VOH + id) * 64 + e];
        }
        fr[960 + t] = acc;
    }
}

// ---------------------------------------------------------------------------
// K5: f32 GEMM C = relu(A@B + bias). 64x64 tile, TK=16, 4x4 micro-tile.
// A [M,K] rm, B [K,N] rm. M%64==0, N%64==0, K%16==0.
// ---------------------------------------------------------------------------
__global__ __launch_bounds__(256) void gemm_bias_relu(const float* __restrict__ A,
                                                      const float* __restrict__ B,
                                                      const float* __restrict__ bias,
                                                      float* __restrict__ C,
                                                      int M, int N, int K, int do_relu)
{
    __shared__ float As[16][68];   // As[kk][m]
    __shared__ float Bs[16][68];   // Bs[kk][n]
    const int t = threadIdx.x;
    const int n0 = blockIdx.x * 64, m0 = blockIdx.y * 64;
    const int ty4 = (t >> 4) << 2, tx4 = (t & 15) << 2;
    float acc[4][4];
#pragma unroll
    for (int i = 0; i < 4; ++i)
#pragma unroll
        for (int j = 0; j < 4; ++j) acc[i][j] = 0.f;

    const int am = t >> 2, ak4 = (t & 3) << 2;
    const int bk = t >> 4, bn4 = (t & 15) << 2;
    for (int k0 = 0; k0 < K; k0 += 16) {
        float4 av = *(const float4*)&A[(size_t)(m0 + am) * K + k0 + ak4];
        As[ak4 + 0][am] = av.x; As[ak4 + 1][am] = av.y;
        As[ak4 + 2][am] = av.z; As[ak4 + 3][am] = av.w;
        *(float4*)&Bs[bk][bn4] = *(const float4*)&B[(size_t)(k0 + bk) * N + n0 + bn4];
        __syncthreads();
#pragma unroll
        for (int kk = 0; kk < 16; ++kk) {
            float4 a = *(const float4*)&As[kk][ty4];
            float4 bb = *(const float4*)&Bs[kk][tx4];
            acc[0][0] += a.x * bb.x; acc[0][1] += a.x * bb.y; acc[0][2] += a.x * bb.z; acc[0][3] += a.x * bb.w;
            acc[1][0] += a.y * bb.x; acc[1][1] += a.y * bb.y; acc[1][2] += a.y * bb.z; acc[1][3] += a.y * bb.w;
            acc[2][0] += a.z * bb.x; acc[2][1] += a.z * bb.y; acc[2][2] += a.z * bb.z; acc[2][3] += a.z * bb.w;
            acc[3][0] += a.w * bb.x; acc[3][1] += a.w * bb.y; acc[3][2] += a.w * bb.z; acc[3][3] += a.w * bb.w;
        }
        __syncthreads();
    }
    const float4 bsv = *(const float4*)&bias[n0 + tx4];
#pragma unroll
    for (int i = 0; i < 4; ++i) {
        float4 v;
        v.x = acc[i][0] + bsv.x; v.y = acc[i][1] + bsv.y;
        v.z = acc[i][2] + bsv.z; v.w = acc[i][3] + bsv.w;
        if (do_relu) {
            v.x = fmaxf(v.x, 0.f); v.y = fmaxf(v.y, 0.f);
            v.z = fmaxf(v.z, 0.f); v.w = fmaxf(v.w, 0.f);
        }
        *(float4*)&C[(size_t)(m0 + ty4 + i) * N + n0 + tx4] = v;
    }
}

// ---------------------------------------------------------------------------
// K6: final 256-dot + bias + sigmoid. One wave per batch row.
// ---------------------------------------------------------------------------
__global__ __launch_bounds__(256) void k_out(const float* __restrict__ x2,
                                             const float* __restrict__ outW,
                                             const float* __restrict__ outb,
                                             float* __restrict__ out)
{
    const int t = threadIdx.x;
    const int wave = t >> 6, lane = t & 63;
    const int row = blockIdx.x * 4 + wave;
    const float4 xv = *(const float4*)&x2[(size_t)row * 256 + lane * 4];
    const float4 wv = *(const float4*)&outW[lane * 4];
    float v = xv.x * wv.x + xv.y * wv.y + xv.z * wv.z + xv.w * wv.w;
    for (int off = 32; off; off >>= 1) v += __shfl_down(v, off);
    if (lane == 0) {
        float lg = v + outb[0];
        out[row] = 1.f / (1.f + expf(-lg));
        out[NB + row] = lg;
    }
}

// ---------------------------------------------------------------------------
extern "C" void kernel_launch(void* const* d_in, const int* in_sizes, int n_in,
                              void* d_out, int out_size, void* d_ws, size_t ws_size,
                              hipStream_t stream)
{
    const float* oh_tab = (const float*)d_in[0];
    const float* mh_tab = (const float*)d_in[1];
    const float* sp_tab = (const float*)d_in[2];
    const float* hw     = (const float*)d_in[3];
    const float* sqW = (const float*)d_in[4];  const float* sqb = (const float*)d_in[5];
    const float* skW = (const float*)d_in[6];  const float* skb = (const float*)d_in[7];
    const float* svW = (const float*)d_in[8];  const float* svb = (const float*)d_in[9];
    const float* soW = (const float*)d_in[10]; const float* sob = (const float*)d_in[11];
    const float* lqW = (const float*)d_in[12]; const float* lqb = (const float*)d_in[13];
    const float* lkW = (const float*)d_in[14]; const float* lkb = (const float*)d_in[15];
    const float* lvW = (const float*)d_in[16]; const float* lvb = (const float*)d_in[17];
    const float* loW = (const float*)d_in[18]; const float* lob = (const float*)d_in[19];
    const float* W0 = (const float*)d_in[20];  const float* b0 = (const float*)d_in[21];
    const float* W1 = (const float*)d_in[22];  const float* b1 = (const float*)d_in[23];
    const float* W2 = (const float*)d_in[24];  const float* b2 = (const float*)d_in[25];
    const float* outW = (const float*)d_in[26]; const float* outb = (const float*)d_in[27];
    const int* oh_ids = (const int*)d_in[28];
    const int* mh_ids = (const int*)d_in[29];
    const int* sp_ids = (const int*)d_in[30];

    // workspace layout (elements): sig[400128] sel[262144] feats[884736]
    // x0[524288] x1[262144] x2[131072]  -> ~9.9 MB total
    unsigned int* sig = (unsigned int*)d_ws;
    int* sel = (int*)d_ws + 400128;
    float* feats = (float*)d_ws + 400128 + 262144;
    float* x0 = feats + 884736;
    float* x1 = x0 + 524288;
    float* x2 = x1 + 262144;

    k_hash<<<(NROWS + 127) / 128, 256, 0, stream>>>(mh_tab, hw, sig);
    k_topk<<<dim3(NB, F_MH), 256, 0, stream>>>(oh_tab, hw, sig, oh_ids, mh_ids, sel);
    k_feats<<<NB, 256, 0, stream>>>(oh_tab, sp_tab, oh_ids, sp_ids, feats);
    k_attn<<<dim3(NB, F_MH, 2), 256, 0, stream>>>(oh_tab, mh_tab, oh_ids, mh_ids, sel,
                                                  sqW, sqb, skW, skb, svW, svb, soW, sob,
                                                  lqW, lqb, lkW, lkb, lvW, lvb, loW, lob,
                                                  feats);
    gemm_bias_relu<<<dim3(16, 8), 256, 0, stream>>>(feats, W0, b0, x0, 512, 1024, 1728, 1);
    gemm_bias_relu<<<dim3(8, 8), 256, 0, stream>>>(x0, W1, b1, x1, 512, 512, 1024, 1);
    gemm_bias_relu<<<dim3(4, 8), 256, 0, stream>>>(x1, W2, b2, x2, 512, 256, 512, 1);
    k_out<<<NB / 4, 256, 0, stream>>>(x2, outW, outb, (float*)d_out);
}

// Round 2
// 649.515 us; speedup vs baseline: 1.0777x; 1.0777x over previous
//
#include <hip/hip_runtime.h>
#include <math.h>

#define F_MH 4
#define NB   512
#define SEQ  2048
#define TOPK 128
#define EDIM 64
#define ADIM 128
#define VOH  10001
#define VMH  100001
#define NROWS (F_MH * VMH)   // 400004
#define D0   1728
#define RSQRT32 0.17677669529663687f

// ---------------------------------------------------------------------------
// K1: per-vocab-row packed LSH signatures. [rows x 64] @ [64 x 32] -> sign bits
// Rewrite (R1): no LDS, no spills. 4 rows/thread, acc[4][8] float4 (128 VGPR).
// hw indexed ONLY by loop counters -> uniform -> compiler emits s_load_dwordx4
// on the scalar pipe (overlaps VALU). VALU-bound at ~10us chip-wide.
// ---------------------------------------------------------------------------
__global__ __launch_bounds__(256) void k_hash(const float* __restrict__ tab,
                                              const float* __restrict__ hw,
                                              unsigned int* __restrict__ sig)
{
    const int t = threadIdx.x;
    const int base = blockIdx.x * 1024 + t;     // rows: base, +256, +512, +768
    const float4* __restrict__ hw4 = (const float4*)hw;   // hw4[e*8 + h4] = cols h4*4..+3 of elem e
    float4 acc[4][8];
#pragma unroll
    for (int i = 0; i < 4; ++i)
#pragma unroll
        for (int h = 0; h < 8; ++h) acc[i][h] = make_float4(0.f, 0.f, 0.f, 0.f);
    int r[4];
    const float4* rp[4];
#pragma unroll
    for (int i = 0; i < 4; ++i) {
        int rr = base + i * 256;
        r[i] = rr;
        rr = (rr < NROWS) ? rr : 0;             // clamp: avoids per-load branches
        rp[i] = (const float4*)(tab + (size_t)rr * 64);
    }
    for (int e4 = 0; e4 < 16; ++e4) {
        float4 x[4];
#pragma unroll
        for (int i = 0; i < 4; ++i) x[i] = rp[i][e4];
#pragma unroll
        for (int j = 0; j < 4; ++j) {
            const int e = e4 * 4 + j;
#pragma unroll
            for (int h = 0; h < 8; ++h) {
                const float4 w = hw4[e * 8 + h];   // uniform -> s_load_dwordx4
#pragma unroll
                for (int i = 0; i < 4; ++i) {
                    const float xs = (j == 0) ? x[i].x : (j == 1) ? x[i].y
                                   : (j == 2) ? x[i].z : x[i].w;
                    acc[i][h].x += xs * w.x; acc[i][h].y += xs * w.y;
                    acc[i][h].z += xs * w.z; acc[i][h].w += xs * w.w;
                }
            }
        }
    }
#pragma unroll
    for (int i = 0; i < 4; ++i) {
        unsigned int bits = 0u;
#pragma unroll
        for (int h = 0; h < 8; ++h) {
            bits |= (acc[i][h].x > 0.f ? 1u : 0u) << (h * 4);
            bits |= (acc[i][h].y > 0.f ? 2u : 0u) << (h * 4);
            bits |= (acc[i][h].z > 0.f ? 4u : 0u) << (h * 4);
            bits |= (acc[i][h].w > 0.f ? 8u : 0u) << (h * 4);
        }
        if (r[i] < NROWS) sig[r[i]] = bits;
    }
}

// ---------------------------------------------------------------------------
// K2: per-(f,b) top-K=128 by Hamming distance. Histogram over d in [0,33],
// threshold D*, stable (lowest-s-first) tie selection == jax.lax.top_k set.
// Stores the selected VOCAB ids directly.
// ---------------------------------------------------------------------------
__global__ __launch_bounds__(256) void k_topk(const float* __restrict__ oh_tab,
                                              const float* __restrict__ hw,
                                              const unsigned int* __restrict__ sig,
                                              const int* __restrict__ oh_ids,
                                              const int* __restrict__ mh_ids,
                                              int* __restrict__ sel)
{
    const int b = blockIdx.x, f = blockIdx.y, t = threadIdx.x;
    __shared__ float tgt[64];
    __shared__ unsigned int thbits;
    __shared__ int hist[34];
    __shared__ int c_lt[256], c_eq[256];
    __shared__ int s_dstar, s_cntlt;
    if (t < 64) tgt[t] = oh_tab[((size_t)f * VOH + oh_ids[b * 15 + f]) * 64 + t];
    if (t == 0) thbits = 0u;
    if (t < 34) hist[t] = 0;
    __syncthreads();
    if (t < 32) {
        float acc = 0.f;
#pragma unroll
        for (int e = 0; e < 64; ++e) acc += tgt[e] * hw[e * 32 + t];
        if (acc > 0.f) atomicOr(&thbits, 1u << t);
    }
    __syncthreads();
    const unsigned int th = thbits;
    const int* idp = mh_ids + (size_t)(f * NB + b) * SEQ + t * 8;
    int ids[8], dv[8];
#pragma unroll
    for (int j = 0; j < 8; ++j) {
        int id = idp[j];
        ids[j] = id;
        int d = (id >= 0) ? __popc(sig[f * VMH + id] ^ th) : 33;
        dv[j] = d;
        atomicAdd(&hist[d], 1);
    }
    __syncthreads();
    if (t == 0) {
        int cum = 0, ds = 33, cl = 0;
        for (int d = 0; d <= 33; ++d) {
            if (cum + hist[d] >= TOPK) { ds = d; cl = cum; break; }
            cum += hist[d];
        }
        s_dstar = ds; s_cntlt = cl;
    }
    __syncthreads();
    const int Dstar = s_dstar, cntlt = s_cntlt;
    int nlt = 0, neq = 0;
#pragma unroll
    for (int j = 0; j < 8; ++j) {
        nlt += (dv[j] < Dstar);
        neq += (dv[j] == Dstar);
    }
    c_lt[t] = nlt; c_eq[t] = neq;
    __syncthreads();
    for (int off = 1; off < 256; off <<= 1) {   // inclusive Hillis-Steele scan
        int vl = 0, ve = 0;
        if (t >= off) { vl = c_lt[t - off]; ve = c_eq[t - off]; }
        __syncthreads();
        c_lt[t] += vl; c_eq[t] += ve;
        __syncthreads();
    }
    int lt_pos = c_lt[t] - nlt;
    int eq_pos = cntlt + c_eq[t] - neq;
    int* selp = sel + (size_t)(f * NB + b) * TOPK;
#pragma unroll
    for (int j = 0; j < 8; ++j) {
        if (dv[j] < Dstar) { selp[lt_pos++] = ids[j]; }
        else if (dv[j] == Dstar) {
            if (eq_pos < TOPK) selp[eq_pos] = ids[j];
            eq_pos++;
        }
    }
}

// ---------------------------------------------------------------------------
// K3: single-query attention (short z=0 / long z=1) with q folded into kW and
// attention weights folded into the embedding (no K/V materialization).
// Writes its 64-float result straight into the feats buffer.
// ---------------------------------------------------------------------------
__global__ __launch_bounds__(256) void k_attn(const float* __restrict__ oh_tab,
                                              const float* __restrict__ mh_tab,
                                              const int* __restrict__ oh_ids,
                                              const int* __restrict__ mh_ids,
                                              const int* __restrict__ sel,
                                              const float* __restrict__ sqW, const float* __restrict__ sqb,
                                              const float* __restrict__ skW, const float* __restrict__ skb,
                                              const float* __restrict__ svW, const float* __restrict__ svb,
                                              const float* __restrict__ soW, const float* __restrict__ sob,
                                              const float* __restrict__ lqW, const float* __restrict__ lqb,
                                              const float* __restrict__ lkW, const float* __restrict__ lkb,
                                              const float* __restrict__ lvW, const float* __restrict__ lvb,
                                              const float* __restrict__ loW, const float* __restrict__ lob,
                                              float* __restrict__ feats)
{
    const int b = blockIdx.x, f = blockIdx.y, z = blockIdx.z, t = threadIdx.x;
    const float* WQ = (z ? lqW : sqW) + (size_t)f * (EDIM * ADIM);
    const float* bq = (z ? lqb : sqb) + f * ADIM;
    const float* WK = (z ? lkW : skW) + (size_t)f * (EDIM * ADIM);
    const float* bk = (z ? lkb : skb) + f * ADIM;
    const float* WV = (z ? lvW : svW) + (size_t)f * (EDIM * ADIM);
    const float* bv = (z ? lvb : svb) + f * ADIM;
    const float* WO = (z ? loW : soW) + (size_t)f * (ADIM * 64);
    const float* bo = (z ? lob : sob) + f * 64;

    __shared__ float tgt[64];
    __shared__ int   sid[128];
    __shared__ float seqT[64][132];   // seqT[e][s], padded (132%4==0)
    __shared__ float qv[128];
    __shared__ float qk[4][64];
    __shared__ float qkb4[4];
    __shared__ float sc[4][128];      // scores, then attn weights in place
    __shared__ float wemb[4][64];
    __shared__ float outv[128];

    if (t < 64) tgt[t] = oh_tab[((size_t)f * VOH + oh_ids[b * 15 + f]) * 64 + t];
    if (t < 128) {
        int id;
        if (z == 0) id = mh_ids[(size_t)(f * NB + b) * SEQ + t];
        else        id = sel[(size_t)(f * NB + b) * TOPK + t];
        sid[t] = id;
    }
    __syncthreads();
    // stage gathered embeddings (transposed)
#pragma unroll
    for (int i = 0; i < 8; ++i) {
        int v = t + i * 256;
        int row = v >> 4, c4 = (v & 15) << 2;
        int id = sid[row];
        float4 ev = make_float4(0.f, 0.f, 0.f, 0.f);
        if (id >= 0) ev = *(const float4*)&mh_tab[((size_t)f * VMH + id) * 64 + c4];
        seqT[c4 + 0][row] = ev.x; seqT[c4 + 1][row] = ev.y;
        seqT[c4 + 2][row] = ev.z; seqT[c4 + 3][row] = ev.w;
    }
    // q projection (1 x 128)
    if (t < 128) {
        float acc = bq[t];
#pragma unroll
        for (int e = 0; e < 64; ++e) acc += tgt[e] * WQ[e * 128 + t];
        qv[t] = acc;
    }
    __syncthreads();
    // fold q into kW: qk[h][e] = (1/sqrt(32)) * sum_d q[h*32+d] * kW[e][h*32+d]
    {
        const int h = t >> 6, e = t & 63;
        float acc = 0.f;
#pragma unroll
        for (int d = 0; d < 32; ++d) acc += qv[h * 32 + d] * WK[e * 128 + h * 32 + d];
        qk[h][e] = acc * RSQRT32;
    }
    if (t < 4) {
        float acc = 0.f;
#pragma unroll
        for (int d = 0; d < 32; ++d) acc += qv[t * 32 + d] * bk[t * 32 + d];
        qkb4[t] = acc * RSQRT32;
    }
    __syncthreads();
    // scores[h][s]
#pragma unroll
    for (int rep = 0; rep < 2; ++rep) {
        int idx = t + rep * 256;
        int h = idx >> 7, s = idx & 127;
        float acc = qkb4[h];
#pragma unroll
        for (int e4 = 0; e4 < 16; ++e4) {
            float4 q4 = *(const float4*)&qk[h][e4 * 4];
            acc += seqT[e4 * 4 + 0][s] * q4.x + seqT[e4 * 4 + 1][s] * q4.y
                 + seqT[e4 * 4 + 2][s] * q4.z + seqT[e4 * 4 + 3][s] * q4.w;
        }
        sc[h][s] = (sid[s] >= 0) ? acc : -INFINITY;
    }
    __syncthreads();
    // softmax: wave w handles head h=w, lanes cover s and s+64
    {
        const int h = t >> 6, l = t & 63;
        float v0 = sc[h][l], v1 = sc[h][l + 64];
        float m = fmaxf(v0, v1);
        for (int off = 32; off; off >>= 1) m = fmaxf(m, __shfl_xor(m, off));
        float p0 = expf(v0 - m), p1 = expf(v1 - m);
        float ssum = p0 + p1;
        for (int off = 32; off; off >>= 1) ssum += __shfl_xor(ssum, off);
        float inv = 1.f / ssum;
        sc[h][l] = p0 * inv; sc[h][l + 64] = p1 * inv;
    }
    __syncthreads();
    // wemb[h][e] = sum_s attn[h][s] * seq[s][e]
    {
        const int h = t >> 6, e = t & 63;
        float acc = 0.f;
#pragma unroll
        for (int s4 = 0; s4 < 32; ++s4) {
            float4 a4 = *(const float4*)&sc[h][s4 * 4];
            float4 e4 = *(const float4*)&seqT[e][s4 * 4];
            acc += a4.x * e4.x + a4.y * e4.y + a4.z * e4.z + a4.w * e4.w;
        }
        wemb[h][e] = acc;
    }
    __syncthreads();
    // out[a] = wemb[h(a)] . vW[:,a] + vb[a]
    if (t < 128) {
        const int h = t >> 5;
        float acc = bv[t];
#pragma unroll
        for (int e = 0; e < 64; ++e) acc += wemb[h][e] * WV[e * 128 + t];
        outv[t] = acc;
    }
    __syncthreads();
    // final[o] = out . oW[:,o] + ob[o] -> feats
    if (t < 64) {
        float acc = bo[t];
#pragma unroll
        for (int a = 0; a < 128; ++a) acc += outv[a] * WO[a * 64 + t];
        feats[(size_t)b * D0 + (z ? 1472 : 1216) + f * 64 + t] = acc;
    }
}

// ---------------------------------------------------------------------------
// K4: feats assembly: one-hot gathers (960) + special sum-pooled (256)
// ---------------------------------------------------------------------------
__global__ __launch_bounds__(256) void k_feats(const float* __restrict__ oh_tab,
                                               const float* __restrict__ sp_tab,
                                               const int* __restrict__ oh_ids,
                                               const int* __restrict__ sp_ids,
                                               float* __restrict__ feats)
{
    const int b = blockIdx.x, t = threadIdx.x;
    __shared__ int sidl[200];
    __shared__ int ohid[15];
    if (t < 200) sidl[t] = sp_ids[(size_t)((t / 50) * NB + b) * 50 + (t % 50)];
    if (t >= 240 && t < 255) ohid[t - 240] = oh_ids[b * 15 + (t - 240)];
    __syncthreads();
    float* fr = feats + (size_t)b * D0;
    for (int p = t; p < 960; p += 256) {
        int f = p >> 6, e = p & 63;
        fr[p] = oh_tab[((size_t)f * VOH + ohid[f]) * 64 + e];
    }
    {
        int f = t >> 6, e = t & 63;
        float acc = 0.f;
        for (int j = 0; j < 50; ++j) {
            int id = sidl[f * 50 + j];
            if (id >= 0) acc += sp_tab[((size_t)f * VOH + id) * 64 + e];
        }
        fr[960 + t] = acc;
    }
}

// ---------------------------------------------------------------------------
// K5: f32 GEMM C = relu(A@B + bias). 64x64 tile, TK=16, 4x4 micro-tile.
// A [M,K] rm, B [K,N] rm. M%64==0, N%64==0, K%16==0.
// ---------------------------------------------------------------------------
__global__ __launch_bounds__(256) void gemm_bias_relu(const float* __restrict__ A,
                                                      const float* __restrict__ B,
                                                      const float* __restrict__ bias,
                                                      float* __restrict__ C,
                                                      int M, int N, int K, int do_relu)
{
    __shared__ float As[16][68];   // As[kk][m]
    __shared__ float Bs[16][68];   // Bs[kk][n]
    const int t = threadIdx.x;
    const int n0 = blockIdx.x * 64, m0 = blockIdx.y * 64;
    const int ty4 = (t >> 4) << 2, tx4 = (t & 15) << 2;
    float acc[4][4];
#pragma unroll
    for (int i = 0; i < 4; ++i)
#pragma unroll
        for (int j = 0; j < 4; ++j) acc[i][j] = 0.f;

    const int am = t >> 2, ak4 = (t & 3) << 2;
    const int bk = t >> 4, bn4 = (t & 15) << 2;
    for (int k0 = 0; k0 < K; k0 += 16) {
        float4 av = *(const float4*)&A[(size_t)(m0 + am) * K + k0 + ak4];
        As[ak4 + 0][am] = av.x; As[ak4 + 1][am] = av.y;
        As[ak4 + 2][am] = av.z; As[ak4 + 3][am] = av.w;
        *(float4*)&Bs[bk][bn4] = *(const float4*)&B[(size_t)(k0 + bk) * N + n0 + bn4];
        __syncthreads();
#pragma unroll
        for (int kk = 0; kk < 16; ++kk) {
            float4 a = *(const float4*)&As[kk][ty4];
            float4 bb = *(const float4*)&Bs[kk][tx4];
            acc[0][0] += a.x * bb.x; acc[0][1] += a.x * bb.y; acc[0][2] += a.x * bb.z; acc[0][3] += a.x * bb.w;
            acc[1][0] += a.y * bb.x; acc[1][1] += a.y * bb.y; acc[1][2] += a.y * bb.z; acc[1][3] += a.y * bb.w;
            acc[2][0] += a.z * bb.x; acc[2][1] += a.z * bb.y; acc[2][2] += a.z * bb.z; acc[2][3] += a.z * bb.w;
            acc[3][0] += a.w * bb.x; acc[3][1] += a.w * bb.y; acc[3][2] += a.w * bb.z; acc[3][3] += a.w * bb.w;
        }
        __syncthreads();
    }
    const float4 bsv = *(const float4*)&bias[n0 + tx4];
#pragma unroll
    for (int i = 0; i < 4; ++i) {
        float4 v;
        v.x = acc[i][0] + bsv.x; v.y = acc[i][1] + bsv.y;
        v.z = acc[i][2] + bsv.z; v.w = acc[i][3] + bsv.w;
        if (do_relu) {
            v.x = fmaxf(v.x, 0.f); v.y = fmaxf(v.y, 0.f);
            v.z = fmaxf(v.z, 0.f); v.w = fmaxf(v.w, 0.f);
        }
        *(float4*)&C[(size_t)(m0 + ty4 + i) * N + n0 + tx4] = v;
    }
}

// ---------------------------------------------------------------------------
// K6: final 256-dot + bias + sigmoid. One wave per batch row.
// ---------------------------------------------------------------------------
__global__ __launch_bounds__(256) void k_out(const float* __restrict__ x2,
                                             const float* __restrict__ outW,
                                             const float* __restrict__ outb,
                                             float* __restrict__ out)
{
    const int t = threadIdx.x;
    const int wave = t >> 6, lane = t & 63;
    const int row = blockIdx.x * 4 + wave;
    const float4 xv = *(const float4*)&x2[(size_t)row * 256 + lane * 4];
    const float4 wv = *(const float4*)&outW[lane * 4];
    float v = xv.x * wv.x + xv.y * wv.y + xv.z * wv.z + xv.w * wv.w;
    for (int off = 32; off; off >>= 1) v += __shfl_down(v, off);
    if (lane == 0) {
        float lg = v + outb[0];
        out[row] = 1.f / (1.f + expf(-lg));
        out[NB + row] = lg;
    }
}

// ---------------------------------------------------------------------------
extern "C" void kernel_launch(void* const* d_in, const int* in_sizes, int n_in,
                              void* d_out, int out_size, void* d_ws, size_t ws_size,
                              hipStream_t stream)
{
    const float* oh_tab = (const float*)d_in[0];
    const float* mh_tab = (const float*)d_in[1];
    const float* sp_tab = (const float*)d_in[2];
    const float* hw     = (const float*)d_in[3];
    const float* sqW = (const float*)d_in[4];  const float* sqb = (const float*)d_in[5];
    const float* skW = (const float*)d_in[6];  const float* skb = (const float*)d_in[7];
    const float* svW = (const float*)d_in[8];  const float* svb = (const float*)d_in[9];
    const float* soW = (const float*)d_in[10]; const float* sob = (const float*)d_in[11];
    const float* lqW = (const float*)d_in[12]; const float* lqb = (const float*)d_in[13];
    const float* lkW = (const float*)d_in[14]; const float* lkb = (const float*)d_in[15];
    const float* lvW = (const float*)d_in[16]; const float* lvb = (const float*)d_in[17];
    const float* loW = (const float*)d_in[18]; const float* lob = (const float*)d_in[19];
    const float* W0 = (const float*)d_in[20];  const float* b0 = (const float*)d_in[21];
    const float* W1 = (const float*)d_in[22];  const float* b1 = (const float*)d_in[23];
    const float* W2 = (const float*)d_in[24];  const float* b2 = (const float*)d_in[25];
    const float* outW = (const float*)d_in[26]; const float* outb = (const float*)d_in[27];
    const int* oh_ids = (const int*)d_in[28];
    const int* mh_ids = (const int*)d_in[29];
    const int* sp_ids = (const int*)d_in[30];

    // workspace layout (elements): sig[400128] sel[262144] feats[884736]
    // x0[524288] x1[262144] x2[131072]  -> ~9.9 MB total
    unsigned int* sig = (unsigned int*)d_ws;
    int* sel = (int*)d_ws + 400128;
    float* feats = (float*)d_ws + 400128 + 262144;
    float* x0 = feats + 884736;
    float* x1 = x0 + 524288;
    float* x2 = x1 + 262144;

    k_hash<<<(NROWS + 1023) / 1024, 256, 0, stream>>>(mh_tab, hw, sig);
    k_topk<<<dim3(NB, F_MH), 256, 0, stream>>>(oh_tab, hw, sig, oh_ids, mh_ids, sel);
    k_feats<<<NB, 256, 0, stream>>>(oh_tab, sp_tab, oh_ids, sp_ids, feats);
    k_attn<<<dim3(NB, F_MH, 2), 256, 0, stream>>>(oh_tab, mh_tab, oh_ids, mh_ids, sel,
                                                  sqW, sqb, skW, skb, svW, svb, soW, sob,
                                                  lqW, lqb, lkW, lkb, lvW, lvb, loW, lob,
                                                  feats);
    gemm_bias_relu<<<dim3(16, 8), 256, 0, stream>>>(feats, W0, b0, x0, 512, 1024, 1728, 1);
    gemm_bias_relu<<<dim3(8, 8), 256, 0, stream>>>(x0, W1, b1, x1, 512, 512, 1024, 1);
    gemm_bias_relu<<<dim3(4, 8), 256, 0, stream>>>(x1, W2, b2, x2, 512, 256, 512, 1);
    k_out<<<NB / 4, 256, 0, stream>>>(x2, outW, outb, (float*)d_out);
}

// Round 3
// 493.734 us; speedup vs baseline: 1.4177x; 1.3155x over previous
//
#include <hip/hip_runtime.h>
#include <math.h>

#define F_MH 4
#define NB   512
#define SEQ  2048
#define TOPK 128
#define EDIM 64
#define ADIM 128
#define VOH  10001
#define VMH  100001
#define NROWS (F_MH * VMH)   // 400004
#define D0   1728
#define RSQRT32 0.17677669529663687f

typedef __bf16 bf16x8 __attribute__((ext_vector_type(8)));
typedef __bf16 bf16x4 __attribute__((ext_vector_type(4)));
typedef float  f32x4  __attribute__((ext_vector_type(4)));

// ---------------------------------------------------------------------------
// K1: per-vocab-row packed LSH signatures (R1 rewrite: no LDS, no spills).
// ---------------------------------------------------------------------------
__global__ __launch_bounds__(256) void k_hash(const float* __restrict__ tab,
                                              const float* __restrict__ hw,
                                              unsigned int* __restrict__ sig)
{
    const int t = threadIdx.x;
    const int base = blockIdx.x * 1024 + t;     // rows: base, +256, +512, +768
    const float4* __restrict__ hw4 = (const float4*)hw;
    float4 acc[4][8];
#pragma unroll
    for (int i = 0; i < 4; ++i)
#pragma unroll
        for (int h = 0; h < 8; ++h) acc[i][h] = make_float4(0.f, 0.f, 0.f, 0.f);
    int r[4];
    const float4* rp[4];
#pragma unroll
    for (int i = 0; i < 4; ++i) {
        int rr = base + i * 256;
        r[i] = rr;
        rr = (rr < NROWS) ? rr : 0;
        rp[i] = (const float4*)(tab + (size_t)rr * 64);
    }
    for (int e4 = 0; e4 < 16; ++e4) {
        float4 x[4];
#pragma unroll
        for (int i = 0; i < 4; ++i) x[i] = rp[i][e4];
#pragma unroll
        for (int j = 0; j < 4; ++j) {
            const int e = e4 * 4 + j;
#pragma unroll
            for (int h = 0; h < 8; ++h) {
                const float4 w = hw4[e * 8 + h];   // uniform -> s_load_dwordx4
#pragma unroll
                for (int i = 0; i < 4; ++i) {
                    const float xs = (j == 0) ? x[i].x : (j == 1) ? x[i].y
                                   : (j == 2) ? x[i].z : x[i].w;
                    acc[i][h].x += xs * w.x; acc[i][h].y += xs * w.y;
                    acc[i][h].z += xs * w.z; acc[i][h].w += xs * w.w;
                }
            }
        }
    }
#pragma unroll
    for (int i = 0; i < 4; ++i) {
        unsigned int bits = 0u;
#pragma unroll
        for (int h = 0; h < 8; ++h) {
            bits |= (acc[i][h].x > 0.f ? 1u : 0u) << (h * 4);
            bits |= (acc[i][h].y > 0.f ? 2u : 0u) << (h * 4);
            bits |= (acc[i][h].z > 0.f ? 4u : 0u) << (h * 4);
            bits |= (acc[i][h].w > 0.f ? 8u : 0u) << (h * 4);
        }
        if (r[i] < NROWS) sig[r[i]] = bits;
    }
}

// ---------------------------------------------------------------------------
// K2: per-(f,b) top-K=128 by Hamming distance (histogram + stable tie pick).
// ---------------------------------------------------------------------------
__global__ __launch_bounds__(256) void k_topk(const float* __restrict__ oh_tab,
                                              const float* __restrict__ hw,
                                              const unsigned int* __restrict__ sig,
                                              const int* __restrict__ oh_ids,
                                              const int* __restrict__ mh_ids,
                                              int* __restrict__ sel)
{
    const int b = blockIdx.x, f = blockIdx.y, t = threadIdx.x;
    __shared__ float tgt[64];
    __shared__ unsigned int thbits;
    __shared__ int hist[34];
    __shared__ int c_lt[256], c_eq[256];
    __shared__ int s_dstar, s_cntlt;
    if (t < 64) tgt[t] = oh_tab[((size_t)f * VOH + oh_ids[b * 15 + f]) * 64 + t];
    if (t == 0) thbits = 0u;
    if (t < 34) hist[t] = 0;
    __syncthreads();
    if (t < 32) {
        float acc = 0.f;
#pragma unroll
        for (int e = 0; e < 64; ++e) acc += tgt[e] * hw[e * 32 + t];
        if (acc > 0.f) atomicOr(&thbits, 1u << t);
    }
    __syncthreads();
    const unsigned int th = thbits;
    const int* idp = mh_ids + (size_t)(f * NB + b) * SEQ + t * 8;
    int ids[8], dv[8];
#pragma unroll
    for (int j = 0; j < 8; ++j) {
        int id = idp[j];
        ids[j] = id;
        int d = (id >= 0) ? __popc(sig[f * VMH + id] ^ th) : 33;
        dv[j] = d;
        atomicAdd(&hist[d], 1);
    }
    __syncthreads();
    if (t == 0) {
        int cum = 0, ds = 33, cl = 0;
        for (int d = 0; d <= 33; ++d) {
            if (cum + hist[d] >= TOPK) { ds = d; cl = cum; break; }
            cum += hist[d];
        }
        s_dstar = ds; s_cntlt = cl;
    }
    __syncthreads();
    const int Dstar = s_dstar, cntlt = s_cntlt;
    int nlt = 0, neq = 0;
#pragma unroll
    for (int j = 0; j < 8; ++j) {
        nlt += (dv[j] < Dstar);
        neq += (dv[j] == Dstar);
    }
    c_lt[t] = nlt; c_eq[t] = neq;
    __syncthreads();
    for (int off = 1; off < 256; off <<= 1) {
        int vl = 0, ve = 0;
        if (t >= off) { vl = c_lt[t - off]; ve = c_eq[t - off]; }
        __syncthreads();
        c_lt[t] += vl; c_eq[t] += ve;
        __syncthreads();
    }
    int lt_pos = c_lt[t] - nlt;
    int eq_pos = cntlt + c_eq[t] - neq;
    int* selp = sel + (size_t)(f * NB + b) * TOPK;
#pragma unroll
    for (int j = 0; j < 8; ++j) {
        if (dv[j] < Dstar) { selp[lt_pos++] = ids[j]; }
        else if (dv[j] == Dstar) {
            if (eq_pos < TOPK) selp[eq_pos] = ids[j];
            eq_pos++;
        }
    }
}

// ---------------------------------------------------------------------------
// K3: single-query attention; output written as bf16 into feats.
// ---------------------------------------------------------------------------
__global__ __launch_bounds__(256) void k_attn(const float* __restrict__ oh_tab,
                                              const float* __restrict__ mh_tab,
                                              const int* __restrict__ oh_ids,
                                              const int* __restrict__ mh_ids,
                                              const int* __restrict__ sel,
                                              const float* __restrict__ sqW, const float* __restrict__ sqb,
                                              const float* __restrict__ skW, const float* __restrict__ skb,
                                              const float* __restrict__ svW, const float* __restrict__ svb,
                                              const float* __restrict__ soW, const float* __restrict__ sob,
                                              const float* __restrict__ lqW, const float* __restrict__ lqb,
                                              const float* __restrict__ lkW, const float* __restrict__ lkb,
                                              const float* __restrict__ lvW, const float* __restrict__ lvb,
                                              const float* __restrict__ loW, const float* __restrict__ lob,
                                              __bf16* __restrict__ feats)
{
    const int b = blockIdx.x, f = blockIdx.y, z = blockIdx.z, t = threadIdx.x;
    const float* WQ = (z ? lqW : sqW) + (size_t)f * (EDIM * ADIM);
    const float* bq = (z ? lqb : sqb) + f * ADIM;
    const float* WK = (z ? lkW : skW) + (size_t)f * (EDIM * ADIM);
    const float* bk = (z ? lkb : skb) + f * ADIM;
    const float* WV = (z ? lvW : svW) + (size_t)f * (EDIM * ADIM);
    const float* bv = (z ? lvb : svb) + f * ADIM;
    const float* WO = (z ? loW : soW) + (size_t)f * (ADIM * 64);
    const float* bo = (z ? lob : sob) + f * 64;

    __shared__ float tgt[64];
    __shared__ int   sid[128];
    __shared__ float seqT[64][132];
    __shared__ float qv[128];
    __shared__ float qk[4][64];
    __shared__ float qkb4[4];
    __shared__ float sc[4][128];
    __shared__ float wemb[4][64];
    __shared__ float outv[128];

    if (t < 64) tgt[t] = oh_tab[((size_t)f * VOH + oh_ids[b * 15 + f]) * 64 + t];
    if (t < 128) {
        int id;
        if (z == 0) id = mh_ids[(size_t)(f * NB + b) * SEQ + t];
        else        id = sel[(size_t)(f * NB + b) * TOPK + t];
        sid[t] = id;
    }
    __syncthreads();
#pragma unroll
    for (int i = 0; i < 8; ++i) {
        int v = t + i * 256;
        int row = v >> 4, c4 = (v & 15) << 2;
        int id = sid[row];
        float4 ev = make_float4(0.f, 0.f, 0.f, 0.f);
        if (id >= 0) ev = *(const float4*)&mh_tab[((size_t)f * VMH + id) * 64 + c4];
        seqT[c4 + 0][row] = ev.x; seqT[c4 + 1][row] = ev.y;
        seqT[c4 + 2][row] = ev.z; seqT[c4 + 3][row] = ev.w;
    }
    if (t < 128) {
        float acc = bq[t];
#pragma unroll
        for (int e = 0; e < 64; ++e) acc += tgt[e] * WQ[e * 128 + t];
        qv[t] = acc;
    }
    __syncthreads();
    {
        const int h = t >> 6, e = t & 63;
        float acc = 0.f;
#pragma unroll
        for (int d = 0; d < 32; ++d) acc += qv[h * 32 + d] * WK[e * 128 + h * 32 + d];
        qk[h][e] = acc * RSQRT32;
    }
    if (t < 4) {
        float acc = 0.f;
#pragma unroll
        for (int d = 0; d < 32; ++d) acc += qv[t * 32 + d] * bk[t * 32 + d];
        qkb4[t] = acc * RSQRT32;
    }
    __syncthreads();
#pragma unroll
    for (int rep = 0; rep < 2; ++rep) {
        int idx = t + rep * 256;
        int h = idx >> 7, s = idx & 127;
        float acc = qkb4[h];
#pragma unroll
        for (int e4 = 0; e4 < 16; ++e4) {
            float4 q4 = *(const float4*)&qk[h][e4 * 4];
            acc += seqT[e4 * 4 + 0][s] * q4.x + seqT[e4 * 4 + 1][s] * q4.y
                 + seqT[e4 * 4 + 2][s] * q4.z + seqT[e4 * 4 + 3][s] * q4.w;
        }
        sc[h][s] = (sid[s] >= 0) ? acc : -INFINITY;
    }
    __syncthreads();
    {
        const int h = t >> 6, l = t & 63;
        float v0 = sc[h][l], v1 = sc[h][l + 64];
        float m = fmaxf(v0, v1);
        for (int off = 32; off; off >>= 1) m = fmaxf(m, __shfl_xor(m, off));
        float p0 = expf(v0 - m), p1 = expf(v1 - m);
        float ssum = p0 + p1;
        for (int off = 32; off; off >>= 1) ssum += __shfl_xor(ssum, off);
        float inv = 1.f / ssum;
        sc[h][l] = p0 * inv; sc[h][l + 64] = p1 * inv;
    }
    __syncthreads();
    {
        const int h = t >> 6, e = t & 63;
        float acc = 0.f;
#pragma unroll
        for (int s4 = 0; s4 < 32; ++s4) {
            float4 a4 = *(const float4*)&sc[h][s4 * 4];
            float4 e4 = *(const float4*)&seqT[e][s4 * 4];
            acc += a4.x * e4.x + a4.y * e4.y + a4.z * e4.z + a4.w * e4.w;
        }
        wemb[h][e] = acc;
    }
    __syncthreads();
    if (t < 128) {
        const int h = t >> 5;
        float acc = bv[t];
#pragma unroll
        for (int e = 0; e < 64; ++e) acc += wemb[h][e] * WV[e * 128 + t];
        outv[t] = acc;
    }
    __syncthreads();
    if (t < 64) {
        float acc = bo[t];
#pragma unroll
        for (int a = 0; a < 128; ++a) acc += outv[a] * WO[a * 64 + t];
        feats[(size_t)b * D0 + (z ? 1472 : 1216) + f * 64 + t] = (__bf16)acc;
    }
}

// ---------------------------------------------------------------------------
// K4: feats assembly (bf16 output)
// ---------------------------------------------------------------------------
__global__ __launch_bounds__(256) void k_feats(const float* __restrict__ oh_tab,
                                               const float* __restrict__ sp_tab,
                                               const int* __restrict__ oh_ids,
                                               const int* __restrict__ sp_ids,
                                               __bf16* __restrict__ feats)
{
    const int b = blockIdx.x, t = threadIdx.x;
    __shared__ int sidl[200];
    __shared__ int ohid[15];
    if (t < 200) sidl[t] = sp_ids[(size_t)((t / 50) * NB + b) * 50 + (t % 50)];
    if (t >= 240 && t < 255) ohid[t - 240] = oh_ids[b * 15 + (t - 240)];
    __syncthreads();
    __bf16* fr = feats + (size_t)b * D0;
    for (int p = t; p < 960; p += 256) {
        int f = p >> 6, e = p & 63;
        fr[p] = (__bf16)oh_tab[((size_t)f * VOH + ohid[f]) * 64 + e];
    }
    {
        int f = t >> 6, e = t & 63;
        float acc = 0.f;
        for (int j = 0; j < 50; ++j) {
            int id = sidl[f * 50 + j];
            if (id >= 0) acc += sp_tab[((size_t)f * VOH + id) * 64 + e];
        }
        fr[960 + t] = (__bf16)acc;
    }
}

// ---------------------------------------------------------------------------
// K5a: weight transpose+convert: W f32 [K][N] -> WT bf16 [N][K]
// ---------------------------------------------------------------------------
__global__ __launch_bounds__(256) void k_trans(const float* __restrict__ W,
                                               __bf16* __restrict__ WT,
                                               int K, int N)
{
    __shared__ float tile[32][33];
    const int t = threadIdx.x;
    const int n0 = blockIdx.x * 32, k0 = blockIdx.y * 32;
    const int c = t & 31, r = t >> 5;
#pragma unroll
    for (int i = 0; i < 4; ++i)
        tile[r + 8 * i][c] = W[(size_t)(k0 + r + 8 * i) * N + n0 + c];
    __syncthreads();
#pragma unroll
    for (int i = 0; i < 4; ++i)
        WT[(size_t)(n0 + r + 8 * i) * K + k0 + c] = (__bf16)tile[c][r + 8 * i];
}

// ---------------------------------------------------------------------------
// K5b: bf16 MFMA GEMM. A [M,K] bf16 rm, BT [N,K] bf16 rm (pre-transposed),
// C = act(A@B + bias) as bf16 [M,N]. 64x64 block tile, 4 waves = 2x2 of 32x32,
// K-step 64. LDS [64][72] (16B pad -> uniform bank groups both phases).
// ---------------------------------------------------------------------------
__global__ __launch_bounds__(256) void gemm_mfma(const __bf16* __restrict__ A,
                                                 const __bf16* __restrict__ BT,
                                                 const float* __restrict__ bias,
                                                 __bf16* __restrict__ C,
                                                 int M, int N, int K, int relu)
{
    __shared__ __bf16 As[64][72];
    __shared__ __bf16 Bs[64][72];
    const int t = threadIdx.x;
    const int n0 = blockIdx.x * 64, m0 = blockIdx.y * 64;
    const int wave = t >> 6, lane = t & 63;
    const int wm = (wave >> 1) * 32, wn = (wave & 1) * 32;
    const int row16 = lane & 15, quad = lane >> 4;
    f32x4 acc[2][2] = {};
    const int sr = t >> 3;           // 0..31
    const int sseg = (t & 7) * 8;    // 0,8,...,56
    for (int k0 = 0; k0 < K; k0 += 64) {
        bf16x8 av0 = *(const bf16x8*)&A[(size_t)(m0 + sr) * K + k0 + sseg];
        bf16x8 av1 = *(const bf16x8*)&A[(size_t)(m0 + sr + 32) * K + k0 + sseg];
        bf16x8 bv0 = *(const bf16x8*)&BT[(size_t)(n0 + sr) * K + k0 + sseg];
        bf16x8 bv1 = *(const bf16x8*)&BT[(size_t)(n0 + sr + 32) * K + k0 + sseg];
        __syncthreads();   // prev iter's LDS reads done
        *(bf16x8*)&As[sr][sseg] = av0;
        *(bf16x8*)&As[sr + 32][sseg] = av1;
        *(bf16x8*)&Bs[sr][sseg] = bv0;
        *(bf16x8*)&Bs[sr + 32][sseg] = bv1;
        __syncthreads();
#pragma unroll
        for (int kk = 0; kk < 2; ++kk) {
            bf16x8 a0 = *(const bf16x8*)&As[wm + row16][kk * 32 + quad * 8];
            bf16x8 a1 = *(const bf16x8*)&As[wm + 16 + row16][kk * 32 + quad * 8];
            bf16x8 b0 = *(const bf16x8*)&Bs[wn + row16][kk * 32 + quad * 8];
            bf16x8 b1 = *(const bf16x8*)&Bs[wn + 16 + row16][kk * 32 + quad * 8];
            acc[0][0] = __builtin_amdgcn_mfma_f32_16x16x32_bf16(a0, b0, acc[0][0], 0, 0, 0);
            acc[0][1] = __builtin_amdgcn_mfma_f32_16x16x32_bf16(a0, b1, acc[0][1], 0, 0, 0);
            acc[1][0] = __builtin_amdgcn_mfma_f32_16x16x32_bf16(a1, b0, acc[1][0], 0, 0, 0);
            acc[1][1] = __builtin_amdgcn_mfma_f32_16x16x32_bf16(a1, b1, acc[1][1], 0, 0, 0);
        }
    }
#pragma unroll
    for (int i = 0; i < 2; ++i)
#pragma unroll
        for (int j = 0; j < 2; ++j) {
            const int col = n0 + wn + j * 16 + row16;
            const float bz = bias[col];
#pragma unroll
            for (int r = 0; r < 4; ++r) {
                const int rowm = m0 + wm + i * 16 + quad * 4 + r;
                float v = acc[i][j][r] + bz;
                if (relu) v = fmaxf(v, 0.f);
                C[(size_t)rowm * N + col] = (__bf16)v;
            }
        }
}

// ---------------------------------------------------------------------------
// K6: final 256-dot + bias + sigmoid (x2 now bf16). One wave per batch row.
// ---------------------------------------------------------------------------
__global__ __launch_bounds__(256) void k_out(const __bf16* __restrict__ x2,
                                             const float* __restrict__ outW,
                                             const float* __restrict__ outb,
                                             float* __restrict__ out)
{
    const int t = threadIdx.x;
    const int wave = t >> 6, lane = t & 63;
    const int row = blockIdx.x * 4 + wave;
    bf16x4 xv = *(const bf16x4*)&x2[(size_t)row * 256 + lane * 4];
    const float4 wv = *(const float4*)&outW[lane * 4];
    float v = (float)xv[0] * wv.x + (float)xv[1] * wv.y
            + (float)xv[2] * wv.z + (float)xv[3] * wv.w;
    for (int off = 32; off; off >>= 1) v += __shfl_down(v, off);
    if (lane == 0) {
        float lg = v + outb[0];
        out[row] = 1.f / (1.f + expf(-lg));
        out[NB + row] = lg;
    }
}

// ---------------------------------------------------------------------------
extern "C" void kernel_launch(void* const* d_in, const int* in_sizes, int n_in,
                              void* d_out, int out_size, void* d_ws, size_t ws_size,
                              hipStream_t stream)
{
    const float* oh_tab = (const float*)d_in[0];
    const float* mh_tab = (const float*)d_in[1];
    const float* sp_tab = (const float*)d_in[2];
    const float* hw     = (const float*)d_in[3];
    const float* sqW = (const float*)d_in[4];  const float* sqb = (const float*)d_in[5];
    const float* skW = (const float*)d_in[6];  const float* skb = (const float*)d_in[7];
    const float* svW = (const float*)d_in[8];  const float* svb = (const float*)d_in[9];
    const float* soW = (const float*)d_in[10]; const float* sob = (const float*)d_in[11];
    const float* lqW = (const float*)d_in[12]; const float* lqb = (const float*)d_in[13];
    const float* lkW = (const float*)d_in[14]; const float* lkb = (const float*)d_in[15];
    const float* lvW = (const float*)d_in[16]; const float* lvb = (const float*)d_in[17];
    const float* loW = (const float*)d_in[18]; const float* lob = (const float*)d_in[19];
    const float* W0 = (const float*)d_in[20];  const float* b0 = (const float*)d_in[21];
    const float* W1 = (const float*)d_in[22];  const float* b1 = (const float*)d_in[23];
    const float* W2 = (const float*)d_in[24];  const float* b2 = (const float*)d_in[25];
    const float* outW = (const float*)d_in[26]; const float* outb = (const float*)d_in[27];
    const int* oh_ids = (const int*)d_in[28];
    const int* mh_ids = (const int*)d_in[29];
    const int* sp_ids = (const int*)d_in[30];

    // workspace layout (bytes, all 16B-aligned):
    char* ws = (char*)d_ws;
    unsigned int* sig = (unsigned int*)(ws + 0);            // 400128 * 4
    int*    sel   = (int*)   (ws + 1600512);                // 262144 * 4
    __bf16* feats = (__bf16*)(ws + 2649088);                // 884736 * 2
    __bf16* x0    = (__bf16*)(ws + 4418560);                // 524288 * 2
    __bf16* x1    = (__bf16*)(ws + 5467136);                // 262144 * 2
    __bf16* x2    = (__bf16*)(ws + 5991424);                // 131072 * 2
    __bf16* WT0   = (__bf16*)(ws + 6253568);                // 1769472 * 2
    __bf16* WT1   = (__bf16*)(ws + 9792512);                // 524288 * 2
    __bf16* WT2   = (__bf16*)(ws + 10841088);               // 131072 * 2

    k_trans<<<dim3(1024 / 32, 1728 / 32), 256, 0, stream>>>(W0, WT0, 1728, 1024);
    k_trans<<<dim3(512 / 32, 1024 / 32), 256, 0, stream>>>(W1, WT1, 1024, 512);
    k_trans<<<dim3(256 / 32, 512 / 32), 256, 0, stream>>>(W2, WT2, 512, 256);

    k_hash<<<(NROWS + 1023) / 1024, 256, 0, stream>>>(mh_tab, hw, sig);
    k_topk<<<dim3(NB, F_MH), 256, 0, stream>>>(oh_tab, hw, sig, oh_ids, mh_ids, sel);
    k_feats<<<NB, 256, 0, stream>>>(oh_tab, sp_tab, oh_ids, sp_ids, feats);
    k_attn<<<dim3(NB, F_MH, 2), 256, 0, stream>>>(oh_tab, mh_tab, oh_ids, mh_ids, sel,
                                                  sqW, sqb, skW, skb, svW, svb, soW, sob,
                                                  lqW, lqb, lkW, lkb, lvW, lvb, loW, lob,
                                                  feats);
    gemm_mfma<<<dim3(16, 8), 256, 0, stream>>>(feats, WT0, b0, x0, 512, 1024, 1728, 1);
    gemm_mfma<<<dim3(8, 8), 256, 0, stream>>>(x0, WT1, b1, x1, 512, 512, 1024, 1);
    gemm_mfma<<<dim3(4, 8), 256, 0, stream>>>(x1, WT2, b2, x2, 512, 256, 512, 1);
    k_out<<<NB / 4, 256, 0, stream>>>(x2, outW, outb, (float*)d_out);
}

// Round 4
// 471.976 us; speedup vs baseline: 1.4830x; 1.0461x over previous
//
#include <hip/hip_runtime.h>
#include <math.h>

#define F_MH 4
#define NB   512
#define SEQ  2048
#define TOPK 128
#define EDIM 64
#define ADIM 128
#define VOH  10001
#define VMH  100001
#define NROWS (F_MH * VMH)   // 400004
#define D0   1728
#define RSQRT32 0.17677669529663687f

typedef __bf16 bf16x8 __attribute__((ext_vector_type(8)));
typedef __bf16 bf16x4 __attribute__((ext_vector_type(4)));
typedef float  f32x4  __attribute__((ext_vector_type(4)));

// ---------------------------------------------------------------------------
// K1 (R3 rewrite): per-vocab-row packed LSH signatures, LDS-staged.
// Block = 128 threads, 128 rows. Global loads fully coalesced (lane-contiguous
// float4) -> every 128B line consumed by one instruction -> no HBM over-fetch.
// LDS pitch 65 dwords: both transposing writes and row reads are 2-way/bank
// (free). Compute: 1 row/thread, acc 8x float4, hw via uniform s_load.
// ---------------------------------------------------------------------------
__global__ __launch_bounds__(128) void k_hash(const float* __restrict__ tab,
                                              const float* __restrict__ hw,
                                              unsigned int* __restrict__ sig)
{
    __shared__ float rows[128][65];
    const int t = threadIdx.x;
    const float4* __restrict__ hw4 = (const float4*)hw;
    // ---- stage 128 rows (8192 dwords) ----
    const size_t blk_dw = (size_t)blockIdx.x * 8192;
    const long long lim = (long long)NROWS * 64 - (long long)blk_dw;  // dwords valid
#pragma unroll
    for (int i = 0; i < 16; ++i) {
        const int idx = i * 512 + t * 4;            // dword index in block region
        float4 v = make_float4(0.f, 0.f, 0.f, 0.f);
        if (idx < lim) v = *(const float4*)(tab + blk_dw + idx);
        const int row = idx >> 6, e = idx & 63;
        rows[row][e + 0] = v.x; rows[row][e + 1] = v.y;
        rows[row][e + 2] = v.z; rows[row][e + 3] = v.w;
    }
    __syncthreads();
    // ---- compute: row t, 32 sign bits ----
    float4 acc[8];
#pragma unroll
    for (int h = 0; h < 8; ++h) acc[h] = make_float4(0.f, 0.f, 0.f, 0.f);
#pragma unroll 16
    for (int e = 0; e < 64; ++e) {
        const float x = rows[t][e];
#pragma unroll
        for (int h = 0; h < 8; ++h) {
            const float4 w = hw4[e * 8 + h];        // uniform -> s_load_dwordx4
            acc[h].x += x * w.x; acc[h].y += x * w.y;
            acc[h].z += x * w.z; acc[h].w += x * w.w;
        }
    }
    unsigned int bits = 0u;
#pragma unroll
    for (int h = 0; h < 8; ++h) {
        bits |= (acc[h].x > 0.f ? 1u : 0u) << (h * 4);
        bits |= (acc[h].y > 0.f ? 2u : 0u) << (h * 4);
        bits |= (acc[h].z > 0.f ? 4u : 0u) << (h * 4);
        bits |= (acc[h].w > 0.f ? 8u : 0u) << (h * 4);
    }
    const int r = blockIdx.x * 128 + t;
    if (r < NROWS) sig[r] = bits;
}

// ---------------------------------------------------------------------------
// K2: per-(f,b) top-K=128 by Hamming distance (histogram + stable tie pick).
// ---------------------------------------------------------------------------
__global__ __launch_bounds__(256) void k_topk(const float* __restrict__ oh_tab,
                                              const float* __restrict__ hw,
                                              const unsigned int* __restrict__ sig,
                                              const int* __restrict__ oh_ids,
                                              const int* __restrict__ mh_ids,
                                              int* __restrict__ sel)
{
    const int b = blockIdx.x, f = blockIdx.y, t = threadIdx.x;
    __shared__ float tgt[64];
    __shared__ unsigned int thbits;
    __shared__ int hist[34];
    __shared__ int c_lt[256], c_eq[256];
    __shared__ int s_dstar, s_cntlt;
    if (t < 64) tgt[t] = oh_tab[((size_t)f * VOH + oh_ids[b * 15 + f]) * 64 + t];
    if (t == 0) thbits = 0u;
    if (t < 34) hist[t] = 0;
    __syncthreads();
    if (t < 32) {
        float acc = 0.f;
#pragma unroll
        for (int e = 0; e < 64; ++e) acc += tgt[e] * hw[e * 32 + t];
        if (acc > 0.f) atomicOr(&thbits, 1u << t);
    }
    __syncthreads();
    const unsigned int th = thbits;
    const int* idp = mh_ids + (size_t)(f * NB + b) * SEQ + t * 8;
    int ids[8], dv[8];
#pragma unroll
    for (int j = 0; j < 8; ++j) {
        int id = idp[j];
        ids[j] = id;
        int d = (id >= 0) ? __popc(sig[f * VMH + id] ^ th) : 33;
        dv[j] = d;
        atomicAdd(&hist[d], 1);
    }
    __syncthreads();
    if (t == 0) {
        int cum = 0, ds = 33, cl = 0;
        for (int d = 0; d <= 33; ++d) {
            if (cum + hist[d] >= TOPK) { ds = d; cl = cum; break; }
            cum += hist[d];
        }
        s_dstar = ds; s_cntlt = cl;
    }
    __syncthreads();
    const int Dstar = s_dstar, cntlt = s_cntlt;
    int nlt = 0, neq = 0;
#pragma unroll
    for (int j = 0; j < 8; ++j) {
        nlt += (dv[j] < Dstar);
        neq += (dv[j] == Dstar);
    }
    c_lt[t] = nlt; c_eq[t] = neq;
    __syncthreads();
    for (int off = 1; off < 256; off <<= 1) {
        int vl = 0, ve = 0;
        if (t >= off) { vl = c_lt[t - off]; ve = c_eq[t - off]; }
        __syncthreads();
        c_lt[t] += vl; c_eq[t] += ve;
        __syncthreads();
    }
    int lt_pos = c_lt[t] - nlt;
    int eq_pos = cntlt + c_eq[t] - neq;
    int* selp = sel + (size_t)(f * NB + b) * TOPK;
#pragma unroll
    for (int j = 0; j < 8; ++j) {
        if (dv[j] < Dstar) { selp[lt_pos++] = ids[j]; }
        else if (dv[j] == Dstar) {
            if (eq_pos < TOPK) selp[eq_pos] = ids[j];
            eq_pos++;
        }
    }
}

// ---------------------------------------------------------------------------
// K3: single-query attention; output written as bf16 into feats.
// ---------------------------------------------------------------------------
__global__ __launch_bounds__(256) void k_attn(const float* __restrict__ oh_tab,
                                              const float* __restrict__ mh_tab,
                                              const int* __restrict__ oh_ids,
                                              const int* __restrict__ mh_ids,
                                              const int* __restrict__ sel,
                                              const float* __restrict__ sqW, const float* __restrict__ sqb,
                                              const float* __restrict__ skW, const float* __restrict__ skb,
                                              const float* __restrict__ svW, const float* __restrict__ svb,
                                              const float* __restrict__ soW, const float* __restrict__ sob,
                                              const float* __restrict__ lqW, const float* __restrict__ lqb,
                                              const float* __restrict__ lkW, const float* __restrict__ lkb,
                                              const float* __restrict__ lvW, const float* __restrict__ lvb,
                                              const float* __restrict__ loW, const float* __restrict__ lob,
                                              __bf16* __restrict__ feats)
{
    const int b = blockIdx.x, f = blockIdx.y, z = blockIdx.z, t = threadIdx.x;
    const float* WQ = (z ? lqW : sqW) + (size_t)f * (EDIM * ADIM);
    const float* bq = (z ? lqb : sqb) + f * ADIM;
    const float* WK = (z ? lkW : skW) + (size_t)f * (EDIM * ADIM);
    const float* bk = (z ? lkb : skb) + f * ADIM;
    const float* WV = (z ? lvW : svW) + (size_t)f * (EDIM * ADIM);
    const float* bv = (z ? lvb : svb) + f * ADIM;
    const float* WO = (z ? loW : soW) + (size_t)f * (ADIM * 64);
    const float* bo = (z ? lob : sob) + f * 64;

    __shared__ float tgt[64];
    __shared__ int   sid[128];
    __shared__ float seqT[64][132];
    __shared__ float qv[128];
    __shared__ float qk[4][64];
    __shared__ float qkb4[4];
    __shared__ float sc[4][128];
    __shared__ float wemb[4][64];
    __shared__ float outv[128];

    if (t < 64) tgt[t] = oh_tab[((size_t)f * VOH + oh_ids[b * 15 + f]) * 64 + t];
    if (t < 128) {
        int id;
        if (z == 0) id = mh_ids[(size_t)(f * NB + b) * SEQ + t];
        else        id = sel[(size_t)(f * NB + b) * TOPK + t];
        sid[t] = id;
    }
    __syncthreads();
#pragma unroll
    for (int i = 0; i < 8; ++i) {
        int v = t + i * 256;
        int row = v >> 4, c4 = (v & 15) << 2;
        int id = sid[row];
        float4 ev = make_float4(0.f, 0.f, 0.f, 0.f);
        if (id >= 0) ev = *(const float4*)&mh_tab[((size_t)f * VMH + id) * 64 + c4];
        seqT[c4 + 0][row] = ev.x; seqT[c4 + 1][row] = ev.y;
        seqT[c4 + 2][row] = ev.z; seqT[c4 + 3][row] = ev.w;
    }
    if (t < 128) {
        float acc = bq[t];
#pragma unroll
        for (int e = 0; e < 64; ++e) acc += tgt[e] * WQ[e * 128 + t];
        qv[t] = acc;
    }
    __syncthreads();
    {
        const int h = t >> 6, e = t & 63;
        float acc = 0.f;
#pragma unroll
        for (int d = 0; d < 32; ++d) acc += qv[h * 32 + d] * WK[e * 128 + h * 32 + d];
        qk[h][e] = acc * RSQRT32;
    }
    if (t < 4) {
        float acc = 0.f;
#pragma unroll
        for (int d = 0; d < 32; ++d) acc += qv[t * 32 + d] * bk[t * 32 + d];
        qkb4[t] = acc * RSQRT32;
    }
    __syncthreads();
#pragma unroll
    for (int rep = 0; rep < 2; ++rep) {
        int idx = t + rep * 256;
        int h = idx >> 7, s = idx & 127;
        float acc = qkb4[h];
#pragma unroll
        for (int e4 = 0; e4 < 16; ++e4) {
            float4 q4 = *(const float4*)&qk[h][e4 * 4];
            acc += seqT[e4 * 4 + 0][s] * q4.x + seqT[e4 * 4 + 1][s] * q4.y
                 + seqT[e4 * 4 + 2][s] * q4.z + seqT[e4 * 4 + 3][s] * q4.w;
        }
        sc[h][s] = (sid[s] >= 0) ? acc : -INFINITY;
    }
    __syncthreads();
    {
        const int h = t >> 6, l = t & 63;
        float v0 = sc[h][l], v1 = sc[h][l + 64];
        float m = fmaxf(v0, v1);
        for (int off = 32; off; off >>= 1) m = fmaxf(m, __shfl_xor(m, off));
        float p0 = expf(v0 - m), p1 = expf(v1 - m);
        float ssum = p0 + p1;
        for (int off = 32; off; off >>= 1) ssum += __shfl_xor(ssum, off);
        float inv = 1.f / ssum;
        sc[h][l] = p0 * inv; sc[h][l + 64] = p1 * inv;
    }
    __syncthreads();
    {
        const int h = t >> 6, e = t & 63;
        float acc = 0.f;
#pragma unroll
        for (int s4 = 0; s4 < 32; ++s4) {
            float4 a4 = *(const float4*)&sc[h][s4 * 4];
            float4 e4 = *(const float4*)&seqT[e][s4 * 4];
            acc += a4.x * e4.x + a4.y * e4.y + a4.z * e4.z + a4.w * e4.w;
        }
        wemb[h][e] = acc;
    }
    __syncthreads();
    if (t < 128) {
        const int h = t >> 5;
        float acc = bv[t];
#pragma unroll
        for (int e = 0; e < 64; ++e) acc += wemb[h][e] * WV[e * 128 + t];
        outv[t] = acc;
    }
    __syncthreads();
    if (t < 64) {
        float acc = bo[t];
#pragma unroll
        for (int a = 0; a < 128; ++a) acc += outv[a] * WO[a * 64 + t];
        feats[(size_t)b * D0 + (z ? 1472 : 1216) + f * 64 + t] = (__bf16)acc;
    }
}

// ---------------------------------------------------------------------------
// K4: feats assembly (bf16 output)
// ---------------------------------------------------------------------------
__global__ __launch_bounds__(256) void k_feats(const float* __restrict__ oh_tab,
                                               const float* __restrict__ sp_tab,
                                               const int* __restrict__ oh_ids,
                                               const int* __restrict__ sp_ids,
                                               __bf16* __restrict__ feats)
{
    const int b = blockIdx.x, t = threadIdx.x;
    __shared__ int sidl[200];
    __shared__ int ohid[15];
    if (t < 200) sidl[t] = sp_ids[(size_t)((t / 50) * NB + b) * 50 + (t % 50)];
    if (t >= 240 && t < 255) ohid[t - 240] = oh_ids[b * 15 + (t - 240)];
    __syncthreads();
    __bf16* fr = feats + (size_t)b * D0;
    for (int p = t; p < 960; p += 256) {
        int f = p >> 6, e = p & 63;
        fr[p] = (__bf16)oh_tab[((size_t)f * VOH + ohid[f]) * 64 + e];
    }
    {
        int f = t >> 6, e = t & 63;
        float acc = 0.f;
        for (int j = 0; j < 50; ++j) {
            int id = sidl[f * 50 + j];
            if (id >= 0) acc += sp_tab[((size_t)f * VOH + id) * 64 + e];
        }
        fr[960 + t] = (__bf16)acc;
    }
}

// ---------------------------------------------------------------------------
// K5a: weight transpose+convert: W f32 [K][N] -> WT bf16 [N][K]
// ---------------------------------------------------------------------------
__global__ __launch_bounds__(256) void k_trans(const float* __restrict__ W,
                                               __bf16* __restrict__ WT,
                                               int K, int N)
{
    __shared__ float tile[32][33];
    const int t = threadIdx.x;
    const int n0 = blockIdx.x * 32, k0 = blockIdx.y * 32;
    const int c = t & 31, r = t >> 5;
#pragma unroll
    for (int i = 0; i < 4; ++i)
        tile[r + 8 * i][c] = W[(size_t)(k0 + r + 8 * i) * N + n0 + c];
    __syncthreads();
#pragma unroll
    for (int i = 0; i < 4; ++i)
        WT[(size_t)(n0 + r + 8 * i) * K + k0 + c] = (__bf16)tile[c][r + 8 * i];
}

// ---------------------------------------------------------------------------
// K5b: bf16 MFMA GEMM. A [M,K] bf16 rm, BT [N,K] bf16 rm (pre-transposed),
// C = act(A@B + bias) as bf16 [M,N]. 64x64 block tile, 4 waves = 2x2 of 32x32,
// K-step 64. LDS [64][72] (16B pad -> uniform bank groups both phases).
// ---------------------------------------------------------------------------
__global__ __launch_bounds__(256) void gemm_mfma(const __bf16* __restrict__ A,
                                                 const __bf16* __restrict__ BT,
                                                 const float* __restrict__ bias,
                                                 __bf16* __restrict__ C,
                                                 int M, int N, int K, int relu)
{
    __shared__ __bf16 As[64][72];
    __shared__ __bf16 Bs[64][72];
    const int t = threadIdx.x;
    const int n0 = blockIdx.x * 64, m0 = blockIdx.y * 64;
    const int wave = t >> 6, lane = t & 63;
    const int wm = (wave >> 1) * 32, wn = (wave & 1) * 32;
    const int row16 = lane & 15, quad = lane >> 4;
    f32x4 acc[2][2] = {};
    const int sr = t >> 3;           // 0..31
    const int sseg = (t & 7) * 8;    // 0,8,...,56
    for (int k0 = 0; k0 < K; k0 += 64) {
        bf16x8 av0 = *(const bf16x8*)&A[(size_t)(m0 + sr) * K + k0 + sseg];
        bf16x8 av1 = *(const bf16x8*)&A[(size_t)(m0 + sr + 32) * K + k0 + sseg];
        bf16x8 bv0 = *(const bf16x8*)&BT[(size_t)(n0 + sr) * K + k0 + sseg];
        bf16x8 bv1 = *(const bf16x8*)&BT[(size_t)(n0 + sr + 32) * K + k0 + sseg];
        __syncthreads();   // prev iter's LDS reads done
        *(bf16x8*)&As[sr][sseg] = av0;
        *(bf16x8*)&As[sr + 32][sseg] = av1;
        *(bf16x8*)&Bs[sr][sseg] = bv0;
        *(bf16x8*)&Bs[sr + 32][sseg] = bv1;
        __syncthreads();
#pragma unroll
        for (int kk = 0; kk < 2; ++kk) {
            bf16x8 a0 = *(const bf16x8*)&As[wm + row16][kk * 32 + quad * 8];
            bf16x8 a1 = *(const bf16x8*)&As[wm + 16 + row16][kk * 32 + quad * 8];
            bf16x8 b0 = *(const bf16x8*)&Bs[wn + row16][kk * 32 + quad * 8];
            bf16x8 b1 = *(const bf16x8*)&Bs[wn + 16 + row16][kk * 32 + quad * 8];
            acc[0][0] = __builtin_amdgcn_mfma_f32_16x16x32_bf16(a0, b0, acc[0][0], 0, 0, 0);
            acc[0][1] = __builtin_amdgcn_mfma_f32_16x16x32_bf16(a0, b1, acc[0][1], 0, 0, 0);
            acc[1][0] = __builtin_amdgcn_mfma_f32_16x16x32_bf16(a1, b0, acc[1][0], 0, 0, 0);
            acc[1][1] = __builtin_amdgcn_mfma_f32_16x16x32_bf16(a1, b1, acc[1][1], 0, 0, 0);
        }
    }
#pragma unroll
    for (int i = 0; i < 2; ++i)
#pragma unroll
        for (int j = 0; j < 2; ++j) {
            const int col = n0 + wn + j * 16 + row16;
            const float bz = bias[col];
#pragma unroll
            for (int r = 0; r < 4; ++r) {
                const int rowm = m0 + wm + i * 16 + quad * 4 + r;
                float v = acc[i][j][r] + bz;
                if (relu) v = fmaxf(v, 0.f);
                C[(size_t)rowm * N + col] = (__bf16)v;
            }
        }
}

// ---------------------------------------------------------------------------
// K6: final 256-dot + bias + sigmoid (x2 bf16). One wave per batch row.
// ---------------------------------------------------------------------------
__global__ __launch_bounds__(256) void k_out(const __bf16* __restrict__ x2,
                                             const float* __restrict__ outW,
                                             const float* __restrict__ outb,
                                             float* __restrict__ out)
{
    const int t = threadIdx.x;
    const int wave = t >> 6, lane = t & 63;
    const int row = blockIdx.x * 4 + wave;
    bf16x4 xv = *(const bf16x4*)&x2[(size_t)row * 256 + lane * 4];
    const float4 wv = *(const float4*)&outW[lane * 4];
    float v = (float)xv[0] * wv.x + (float)xv[1] * wv.y
            + (float)xv[2] * wv.z + (float)xv[3] * wv.w;
    for (int off = 32; off; off >>= 1) v += __shfl_down(v, off);
    if (lane == 0) {
        float lg = v + outb[0];
        out[row] = 1.f / (1.f + expf(-lg));
        out[NB + row] = lg;
    }
}

// ---------------------------------------------------------------------------
extern "C" void kernel_launch(void* const* d_in, const int* in_sizes, int n_in,
                              void* d_out, int out_size, void* d_ws, size_t ws_size,
                              hipStream_t stream)
{
    const float* oh_tab = (const float*)d_in[0];
    const float* mh_tab = (const float*)d_in[1];
    const float* sp_tab = (const float*)d_in[2];
    const float* hw     = (const float*)d_in[3];
    const float* sqW = (const float*)d_in[4];  const float* sqb = (const float*)d_in[5];
    const float* skW = (const float*)d_in[6];  const float* skb = (const float*)d_in[7];
    const float* svW = (const float*)d_in[8];  const float* svb = (const float*)d_in[9];
    const float* soW = (const float*)d_in[10]; const float* sob = (const float*)d_in[11];
    const float* lqW = (const float*)d_in[12]; const float* lqb = (const float*)d_in[13];
    const float* lkW = (const float*)d_in[14]; const float* lkb = (const float*)d_in[15];
    const float* lvW = (const float*)d_in[16]; const float* lvb = (const float*)d_in[17];
    const float* loW = (const float*)d_in[18]; const float* lob = (const float*)d_in[19];
    const float* W0 = (const float*)d_in[20];  const float* b0 = (const float*)d_in[21];
    const float* W1 = (const float*)d_in[22];  const float* b1 = (const float*)d_in[23];
    const float* W2 = (const float*)d_in[24];  const float* b2 = (const float*)d_in[25];
    const float* outW = (const float*)d_in[26]; const float* outb = (const float*)d_in[27];
    const int* oh_ids = (const int*)d_in[28];
    const int* mh_ids = (const int*)d_in[29];
    const int* sp_ids = (const int*)d_in[30];

    // workspace layout (bytes, all 16B-aligned):
    char* ws = (char*)d_ws;
    unsigned int* sig = (unsigned int*)(ws + 0);            // 400128 * 4
    int*    sel   = (int*)   (ws + 1600512);                // 262144 * 4
    __bf16* feats = (__bf16*)(ws + 2649088);                // 884736 * 2
    __bf16* x0    = (__bf16*)(ws + 4418560);                // 524288 * 2
    __bf16* x1    = (__bf16*)(ws + 5467136);                // 262144 * 2
    __bf16* x2    = (__bf16*)(ws + 5991424);                // 131072 * 2
    __bf16* WT0   = (__bf16*)(ws + 6253568);                // 1769472 * 2
    __bf16* WT1   = (__bf16*)(ws + 9792512);                // 524288 * 2
    __bf16* WT2   = (__bf16*)(ws + 10841088);               // 131072 * 2

    k_trans<<<dim3(1024 / 32, 1728 / 32), 256, 0, stream>>>(W0, WT0, 1728, 1024);
    k_trans<<<dim3(512 / 32, 1024 / 32), 256, 0, stream>>>(W1, WT1, 1024, 512);
    k_trans<<<dim3(256 / 32, 512 / 32), 256, 0, stream>>>(W2, WT2, 512, 256);

    k_hash<<<(NROWS + 127) / 128, 128, 0, stream>>>(mh_tab, hw, sig);
    k_topk<<<dim3(NB, F_MH), 256, 0, stream>>>(oh_tab, hw, sig, oh_ids, mh_ids, sel);
    k_feats<<<NB, 256, 0, stream>>>(oh_tab, sp_tab, oh_ids, sp_ids, feats);
    k_attn<<<dim3(NB, F_MH, 2), 256, 0, stream>>>(oh_tab, mh_tab, oh_ids, mh_ids, sel,
                                                  sqW, sqb, skW, skb, svW, svb, soW, sob,
                                                  lqW, lqb, lkW, lkb, lvW, lvb, loW, lob,
                                                  feats);
    gemm_mfma<<<dim3(16, 8), 256, 0, stream>>>(feats, WT0, b0, x0, 512, 1024, 1728, 1);
    gemm_mfma<<<dim3(8, 8), 256, 0, stream>>>(x0, WT1, b1, x1, 512, 512, 1024, 1);
    gemm_mfma<<<dim3(4, 8), 256, 0, stream>>>(x1, WT2, b2, x2, 512, 256, 512, 1);
    k_out<<<NB / 4, 256, 0, stream>>>(x2, outW, outb, (float*)d_out);
}

// Round 5
// 466.641 us; speedup vs baseline: 1.5000x; 1.0114x over previous
//
#include <hip/hip_runtime.h>
#include <math.h>

#define F_MH 4
#define NB   512
#define SEQ  2048
#define TOPK 128
#define EDIM 64
#define ADIM 128
#define VOH  10001
#define VMH  100001
#define NROWS (F_MH * VMH)   // 400004
#define D0   1728
#define RSQRT32 0.17677669529663687f

typedef __bf16 bf16x8 __attribute__((ext_vector_type(8)));
typedef __bf16 bf16x4 __attribute__((ext_vector_type(4)));
typedef float  f32x4  __attribute__((ext_vector_type(4)));

// ---------------------------------------------------------------------------
// K1 (R4 rewrite): LSH signatures, software-pipelined.
// Block = 128 threads owns 512 rows in 4 chunks of 128. Chunk c+1 is
// prefetched into registers (16 x float4) while chunk c computes from LDS ->
// vmcnt wait lands after ~4096 cyc of compute; memory stays busy.
// Coalesced lane-contiguous float4 loads (no over-fetch, per R3). LDS pitch
// 65 dwords: writes and per-row reads both 2-way/bank (free).
// ---------------------------------------------------------------------------
__global__ __launch_bounds__(128) void k_hash(const float* __restrict__ tab,
                                              const float* __restrict__ hw,
                                              unsigned int* __restrict__ sig)
{
    __shared__ float rows[128][65];
    const int t = threadIdx.x;
    const float4* __restrict__ hw4 = (const float4*)hw;
    const long long base_dw = (long long)blockIdx.x * 32768;   // 512 rows * 64
    const long long lim = (long long)NROWS * 64;
    float4 pf[16];
#pragma unroll
    for (int i = 0; i < 16; ++i) {
        const long long idx = base_dw + i * 512 + t * 4;
        pf[i] = make_float4(0.f, 0.f, 0.f, 0.f);
        if (idx < lim) pf[i] = *(const float4*)(tab + idx);
    }
    for (int c = 0; c < 4; ++c) {
        __syncthreads();              // prior chunk's LDS reads done
#pragma unroll
        for (int i = 0; i < 16; ++i) {
            const int idx = i * 512 + t * 4;
            const int row = idx >> 6, e = idx & 63;
            rows[row][e + 0] = pf[i].x; rows[row][e + 1] = pf[i].y;
            rows[row][e + 2] = pf[i].z; rows[row][e + 3] = pf[i].w;
        }
        __syncthreads();
        if (c < 3) {                  // prefetch next chunk (hidden under compute)
#pragma unroll
            for (int i = 0; i < 16; ++i) {
                const long long idx = base_dw + (long long)(c + 1) * 8192 + i * 512 + t * 4;
                pf[i] = make_float4(0.f, 0.f, 0.f, 0.f);
                if (idx < lim) pf[i] = *(const float4*)(tab + idx);
            }
        }
        // ---- compute: row t of chunk c, 32 sign bits ----
        float4 acc[8];
#pragma unroll
        for (int h = 0; h < 8; ++h) acc[h] = make_float4(0.f, 0.f, 0.f, 0.f);
#pragma unroll 16
        for (int e = 0; e < 64; ++e) {
            const float x = rows[t][e];
#pragma unroll
            for (int h = 0; h < 8; ++h) {
                const float4 w = hw4[e * 8 + h];    // uniform -> s_load_dwordx4
                acc[h].x += x * w.x; acc[h].y += x * w.y;
                acc[h].z += x * w.z; acc[h].w += x * w.w;
            }
        }
        unsigned int bits = 0u;
#pragma unroll
        for (int h = 0; h < 8; ++h) {
            bits |= (acc[h].x > 0.f ? 1u : 0u) << (h * 4);
            bits |= (acc[h].y > 0.f ? 2u : 0u) << (h * 4);
            bits |= (acc[h].z > 0.f ? 4u : 0u) << (h * 4);
            bits |= (acc[h].w > 0.f ? 8u : 0u) << (h * 4);
        }
        const int r = blockIdx.x * 512 + c * 128 + t;
        if (r < NROWS) sig[r] = bits;
    }
}

// ---------------------------------------------------------------------------
// K2: per-(f,b) top-K=128 by Hamming distance (histogram + stable tie pick).
// ---------------------------------------------------------------------------
__global__ __launch_bounds__(256) void k_topk(const float* __restrict__ oh_tab,
                                              const float* __restrict__ hw,
                                              const unsigned int* __restrict__ sig,
                                              const int* __restrict__ oh_ids,
                                              const int* __restrict__ mh_ids,
                                              int* __restrict__ sel)
{
    const int b = blockIdx.x, f = blockIdx.y, t = threadIdx.x;
    __shared__ float tgt[64];
    __shared__ unsigned int thbits;
    __shared__ int hist[34];
    __shared__ int c_lt[256], c_eq[256];
    __shared__ int s_dstar, s_cntlt;
    if (t < 64) tgt[t] = oh_tab[((size_t)f * VOH + oh_ids[b * 15 + f]) * 64 + t];
    if (t == 0) thbits = 0u;
    if (t < 34) hist[t] = 0;
    __syncthreads();
    if (t < 32) {
        float acc = 0.f;
#pragma unroll
        for (int e = 0; e < 64; ++e) acc += tgt[e] * hw[e * 32 + t];
        if (acc > 0.f) atomicOr(&thbits, 1u << t);
    }
    __syncthreads();
    const unsigned int th = thbits;
    const int* idp = mh_ids + (size_t)(f * NB + b) * SEQ + t * 8;
    int ids[8], dv[8];
#pragma unroll
    for (int j = 0; j < 8; ++j) {
        int id = idp[j];
        ids[j] = id;
        int d = (id >= 0) ? __popc(sig[f * VMH + id] ^ th) : 33;
        dv[j] = d;
        atomicAdd(&hist[d], 1);
    }
    __syncthreads();
    if (t == 0) {
        int cum = 0, ds = 33, cl = 0;
        for (int d = 0; d <= 33; ++d) {
            if (cum + hist[d] >= TOPK) { ds = d; cl = cum; break; }
            cum += hist[d];
        }
        s_dstar = ds; s_cntlt = cl;
    }
    __syncthreads();
    const int Dstar = s_dstar, cntlt = s_cntlt;
    int nlt = 0, neq = 0;
#pragma unroll
    for (int j = 0; j < 8; ++j) {
        nlt += (dv[j] < Dstar);
        neq += (dv[j] == Dstar);
    }
    c_lt[t] = nlt; c_eq[t] = neq;
    __syncthreads();
    for (int off = 1; off < 256; off <<= 1) {
        int vl = 0, ve = 0;
        if (t >= off) { vl = c_lt[t - off]; ve = c_eq[t - off]; }
        __syncthreads();
        c_lt[t] += vl; c_eq[t] += ve;
        __syncthreads();
    }
    int lt_pos = c_lt[t] - nlt;
    int eq_pos = cntlt + c_eq[t] - neq;
    int* selp = sel + (size_t)(f * NB + b) * TOPK;
#pragma unroll
    for (int j = 0; j < 8; ++j) {
        if (dv[j] < Dstar) { selp[lt_pos++] = ids[j]; }
        else if (dv[j] == Dstar) {
            if (eq_pos < TOPK) selp[eq_pos] = ids[j];
            eq_pos++;
        }
    }
}

// ---------------------------------------------------------------------------
// K3: single-query attention; output written as bf16 into feats.
// ---------------------------------------------------------------------------
__global__ __launch_bounds__(256) void k_attn(const float* __restrict__ oh_tab,
                                              const float* __restrict__ mh_tab,
                                              const int* __restrict__ oh_ids,
                                              const int* __restrict__ mh_ids,
                                              const int* __restrict__ sel,
                                              const float* __restrict__ sqW, const float* __restrict__ sqb,
                                              const float* __restrict__ skW, const float* __restrict__ skb,
                                              const float* __restrict__ svW, const float* __restrict__ svb,
                                              const float* __restrict__ soW, const float* __restrict__ sob,
                                              const float* __restrict__ lqW, const float* __restrict__ lqb,
                                              const float* __restrict__ lkW, const float* __restrict__ lkb,
                                              const float* __restrict__ lvW, const float* __restrict__ lvb,
                                              const float* __restrict__ loW, const float* __restrict__ lob,
                                              __bf16* __restrict__ feats)
{
    const int b = blockIdx.x, f = blockIdx.y, z = blockIdx.z, t = threadIdx.x;
    const float* WQ = (z ? lqW : sqW) + (size_t)f * (EDIM * ADIM);
    const float* bq = (z ? lqb : sqb) + f * ADIM;
    const float* WK = (z ? lkW : skW) + (size_t)f * (EDIM * ADIM);
    const float* bk = (z ? lkb : skb) + f * ADIM;
    const float* WV = (z ? lvW : svW) + (size_t)f * (EDIM * ADIM);
    const float* bv = (z ? lvb : svb) + f * ADIM;
    const float* WO = (z ? loW : soW) + (size_t)f * (ADIM * 64);
    const float* bo = (z ? lob : sob) + f * 64;

    __shared__ float tgt[64];
    __shared__ int   sid[128];
    __shared__ float seqT[64][132];
    __shared__ float qv[128];
    __shared__ float qk[4][64];
    __shared__ float qkb4[4];
    __shared__ float sc[4][128];
    __shared__ float wemb[4][64];
    __shared__ float outv[128];

    if (t < 64) tgt[t] = oh_tab[((size_t)f * VOH + oh_ids[b * 15 + f]) * 64 + t];
    if (t < 128) {
        int id;
        if (z == 0) id = mh_ids[(size_t)(f * NB + b) * SEQ + t];
        else        id = sel[(size_t)(f * NB + b) * TOPK + t];
        sid[t] = id;
    }
    __syncthreads();
#pragma unroll
    for (int i = 0; i < 8; ++i) {
        int v = t + i * 256;
        int row = v >> 4, c4 = (v & 15) << 2;
        int id = sid[row];
        float4 ev = make_float4(0.f, 0.f, 0.f, 0.f);
        if (id >= 0) ev = *(const float4*)&mh_tab[((size_t)f * VMH + id) * 64 + c4];
        seqT[c4 + 0][row] = ev.x; seqT[c4 + 1][row] = ev.y;
        seqT[c4 + 2][row] = ev.z; seqT[c4 + 3][row] = ev.w;
    }
    if (t < 128) {
        float acc = bq[t];
#pragma unroll
        for (int e = 0; e < 64; ++e) acc += tgt[e] * WQ[e * 128 + t];
        qv[t] = acc;
    }
    __syncthreads();
    {
        const int h = t >> 6, e = t & 63;
        float acc = 0.f;
#pragma unroll
        for (int d = 0; d < 32; ++d) acc += qv[h * 32 + d] * WK[e * 128 + h * 32 + d];
        qk[h][e] = acc * RSQRT32;
    }
    if (t < 4) {
        float acc = 0.f;
#pragma unroll
        for (int d = 0; d < 32; ++d) acc += qv[t * 32 + d] * bk[t * 32 + d];
        qkb4[t] = acc * RSQRT32;
    }
    __syncthreads();
#pragma unroll
    for (int rep = 0; rep < 2; ++rep) {
        int idx = t + rep * 256;
        int h = idx >> 7, s = idx & 127;
        float acc = qkb4[h];
#pragma unroll
        for (int e4 = 0; e4 < 16; ++e4) {
            float4 q4 = *(const float4*)&qk[h][e4 * 4];
            acc += seqT[e4 * 4 + 0][s] * q4.x + seqT[e4 * 4 + 1][s] * q4.y
                 + seqT[e4 * 4 + 2][s] * q4.z + seqT[e4 * 4 + 3][s] * q4.w;
        }
        sc[h][s] = (sid[s] >= 0) ? acc : -INFINITY;
    }
    __syncthreads();
    {
        const int h = t >> 6, l = t & 63;
        float v0 = sc[h][l], v1 = sc[h][l + 64];
        float m = fmaxf(v0, v1);
        for (int off = 32; off; off >>= 1) m = fmaxf(m, __shfl_xor(m, off));
        float p0 = expf(v0 - m), p1 = expf(v1 - m);
        float ssum = p0 + p1;
        for (int off = 32; off; off >>= 1) ssum += __shfl_xor(ssum, off);
        float inv = 1.f / ssum;
        sc[h][l] = p0 * inv; sc[h][l + 64] = p1 * inv;
    }
    __syncthreads();
    {
        const int h = t >> 6, e = t & 63;
        float acc = 0.f;
#pragma unroll
        for (int s4 = 0; s4 < 32; ++s4) {
            float4 a4 = *(const float4*)&sc[h][s4 * 4];
            float4 e4 = *(const float4*)&seqT[e][s4 * 4];
            acc += a4.x * e4.x + a4.y * e4.y + a4.z * e4.z + a4.w * e4.w;
        }
        wemb[h][e] = acc;
    }
    __syncthreads();
    if (t < 128) {
        const int h = t >> 5;
        float acc = bv[t];
#pragma unroll
        for (int e = 0; e < 64; ++e) acc += wemb[h][e] * WV[e * 128 + t];
        outv[t] = acc;
    }
    __syncthreads();
    if (t < 64) {
        float acc = bo[t];
#pragma unroll
        for (int a = 0; a < 128; ++a) acc += outv[a] * WO[a * 64 + t];
        feats[(size_t)b * D0 + (z ? 1472 : 1216) + f * 64 + t] = (__bf16)acc;
    }
}

// ---------------------------------------------------------------------------
// K4: feats assembly (bf16 output)
// ---------------------------------------------------------------------------
__global__ __launch_bounds__(256) void k_feats(const float* __restrict__ oh_tab,
                                               const float* __restrict__ sp_tab,
                                               const int* __restrict__ oh_ids,
                                               const int* __restrict__ sp_ids,
                                               __bf16* __restrict__ feats)
{
    const int b = blockIdx.x, t = threadIdx.x;
    __shared__ int sidl[200];
    __shared__ int ohid[15];
    if (t < 200) sidl[t] = sp_ids[(size_t)((t / 50) * NB + b) * 50 + (t % 50)];
    if (t >= 240 && t < 255) ohid[t - 240] = oh_ids[b * 15 + (t - 240)];
    __syncthreads();
    __bf16* fr = feats + (size_t)b * D0;
    for (int p = t; p < 960; p += 256) {
        int f = p >> 6, e = p & 63;
        fr[p] = (__bf16)oh_tab[((size_t)f * VOH + ohid[f]) * 64 + e];
    }
    {
        int f = t >> 6, e = t & 63;
        float acc = 0.f;
        for (int j = 0; j < 50; ++j) {
            int id = sidl[f * 50 + j];
            if (id >= 0) acc += sp_tab[((size_t)f * VOH + id) * 64 + e];
        }
        fr[960 + t] = (__bf16)acc;
    }
}

// ---------------------------------------------------------------------------
// K5a: weight transpose+convert: W f32 [K][N] -> WT bf16 [N][K]
// ---------------------------------------------------------------------------
__global__ __launch_bounds__(256) void k_trans(const float* __restrict__ W,
                                               __bf16* __restrict__ WT,
                                               int K, int N)
{
    __shared__ float tile[32][33];
    const int t = threadIdx.x;
    const int n0 = blockIdx.x * 32, k0 = blockIdx.y * 32;
    const int c = t & 31, r = t >> 5;
#pragma unroll
    for (int i = 0; i < 4; ++i)
        tile[r + 8 * i][c] = W[(size_t)(k0 + r + 8 * i) * N + n0 + c];
    __syncthreads();
#pragma unroll
    for (int i = 0; i < 4; ++i)
        WT[(size_t)(n0 + r + 8 * i) * K + k0 + c] = (__bf16)tile[c][r + 8 * i];
}

// ---------------------------------------------------------------------------
// K5b: bf16 MFMA GEMM. A [M,K] bf16 rm, BT [N,K] bf16 rm (pre-transposed),
// C = act(A@B + bias) as bf16 [M,N]. 64x64 block tile, 4 waves = 2x2 of 32x32,
// K-step 64. LDS [64][72] (16B pad -> uniform bank groups both phases).
// ---------------------------------------------------------------------------
__global__ __launch_bounds__(256) void gemm_mfma(const __bf16* __restrict__ A,
                                                 const __bf16* __restrict__ BT,
                                                 const float* __restrict__ bias,
                                                 __bf16* __restrict__ C,
                                                 int M, int N, int K, int relu)
{
    __shared__ __bf16 As[64][72];
    __shared__ __bf16 Bs[64][72];
    const int t = threadIdx.x;
    const int n0 = blockIdx.x * 64, m0 = blockIdx.y * 64;
    const int wave = t >> 6, lane = t & 63;
    const int wm = (wave >> 1) * 32, wn = (wave & 1) * 32;
    const int row16 = lane & 15, quad = lane >> 4;
    f32x4 acc[2][2] = {};
    const int sr = t >> 3;           // 0..31
    const int sseg = (t & 7) * 8;    // 0,8,...,56
    for (int k0 = 0; k0 < K; k0 += 64) {
        bf16x8 av0 = *(const bf16x8*)&A[(size_t)(m0 + sr) * K + k0 + sseg];
        bf16x8 av1 = *(const bf16x8*)&A[(size_t)(m0 + sr + 32) * K + k0 + sseg];
        bf16x8 bv0 = *(const bf16x8*)&BT[(size_t)(n0 + sr) * K + k0 + sseg];
        bf16x8 bv1 = *(const bf16x8*)&BT[(size_t)(n0 + sr + 32) * K + k0 + sseg];
        __syncthreads();   // prev iter's LDS reads done
        *(bf16x8*)&As[sr][sseg] = av0;
        *(bf16x8*)&As[sr + 32][sseg] = av1;
        *(bf16x8*)&Bs[sr][sseg] = bv0;
        *(bf16x8*)&Bs[sr + 32][sseg] = bv1;
        __syncthreads();
#pragma unroll
        for (int kk = 0; kk < 2; ++kk) {
            bf16x8 a0 = *(const bf16x8*)&As[wm + row16][kk * 32 + quad * 8];
            bf16x8 a1 = *(const bf16x8*)&As[wm + 16 + row16][kk * 32 + quad * 8];
            bf16x8 b0 = *(const bf16x8*)&Bs[wn + row16][kk * 32 + quad * 8];
            bf16x8 b1 = *(const bf16x8*)&Bs[wn + 16 + row16][kk * 32 + quad * 8];
            acc[0][0] = __builtin_amdgcn_mfma_f32_16x16x32_bf16(a0, b0, acc[0][0], 0, 0, 0);
            acc[0][1] = __builtin_amdgcn_mfma_f32_16x16x32_bf16(a0, b1, acc[0][1], 0, 0, 0);
            acc[1][0] = __builtin_amdgcn_mfma_f32_16x16x32_bf16(a1, b0, acc[1][0], 0, 0, 0);
            acc[1][1] = __builtin_amdgcn_mfma_f32_16x16x32_bf16(a1, b1, acc[1][1], 0, 0, 0);
        }
    }
#pragma unroll
    for (int i = 0; i < 2; ++i)
#pragma unroll
        for (int j = 0; j < 2; ++j) {
            const int col = n0 + wn + j * 16 + row16;
            const float bz = bias[col];
#pragma unroll
            for (int r = 0; r < 4; ++r) {
                const int rowm = m0 + wm + i * 16 + quad * 4 + r;
                float v = acc[i][j][r] + bz;
                if (relu) v = fmaxf(v, 0.f);
                C[(size_t)rowm * N + col] = (__bf16)v;
            }
        }
}

// ---------------------------------------------------------------------------
// K6: final 256-dot + bias + sigmoid (x2 bf16). One wave per batch row.
// ---------------------------------------------------------------------------
__global__ __launch_bounds__(256) void k_out(const __bf16* __restrict__ x2,
                                             const float* __restrict__ outW,
                                             const float* __restrict__ outb,
                                             float* __restrict__ out)
{
    const int t = threadIdx.x;
    const int wave = t >> 6, lane = t & 63;
    const int row = blockIdx.x * 4 + wave;
    bf16x4 xv = *(const bf16x4*)&x2[(size_t)row * 256 + lane * 4];
    const float4 wv = *(const float4*)&outW[lane * 4];
    float v = (float)xv[0] * wv.x + (float)xv[1] * wv.y
            + (float)xv[2] * wv.z + (float)xv[3] * wv.w;
    for (int off = 32; off; off >>= 1) v += __shfl_down(v, off);
    if (lane == 0) {
        float lg = v + outb[0];
        out[row] = 1.f / (1.f + expf(-lg));
        out[NB + row] = lg;
    }
}

// ---------------------------------------------------------------------------
extern "C" void kernel_launch(void* const* d_in, const int* in_sizes, int n_in,
                              void* d_out, int out_size, void* d_ws, size_t ws_size,
                              hipStream_t stream)
{
    const float* oh_tab = (const float*)d_in[0];
    const float* mh_tab = (const float*)d_in[1];
    const float* sp_tab = (const float*)d_in[2];
    const float* hw     = (const float*)d_in[3];
    const float* sqW = (const float*)d_in[4];  const float* sqb = (const float*)d_in[5];
    const float* skW = (const float*)d_in[6];  const float* skb = (const float*)d_in[7];
    const float* svW = (const float*)d_in[8];  const float* svb = (const float*)d_in[9];
    const float* soW = (const float*)d_in[10]; const float* sob = (const float*)d_in[11];
    const float* lqW = (const float*)d_in[12]; const float* lqb = (const float*)d_in[13];
    const float* lkW = (const float*)d_in[14]; const float* lkb = (const float*)d_in[15];
    const float* lvW = (const float*)d_in[16]; const float* lvb = (const float*)d_in[17];
    const float* loW = (const float*)d_in[18]; const float* lob = (const float*)d_in[19];
    const float* W0 = (const float*)d_in[20];  const float* b0 = (const float*)d_in[21];
    const float* W1 = (const float*)d_in[22];  const float* b1 = (const float*)d_in[23];
    const float* W2 = (const float*)d_in[24];  const float* b2 = (const float*)d_in[25];
    const float* outW = (const float*)d_in[26]; const float* outb = (const float*)d_in[27];
    const int* oh_ids = (const int*)d_in[28];
    const int* mh_ids = (const int*)d_in[29];
    const int* sp_ids = (const int*)d_in[30];

    // workspace layout (bytes, all 16B-aligned):
    char* ws = (char*)d_ws;
    unsigned int* sig = (unsigned int*)(ws + 0);            // 400128 * 4
    int*    sel   = (int*)   (ws + 1600512);                // 262144 * 4
    __bf16* feats = (__bf16*)(ws + 2649088);                // 884736 * 2
    __bf16* x0    = (__bf16*)(ws + 4418560);                // 524288 * 2
    __bf16* x1    = (__bf16*)(ws + 5467136);                // 262144 * 2
    __bf16* x2    = (__bf16*)(ws + 5991424);                // 131072 * 2
    __bf16* WT0   = (__bf16*)(ws + 6253568);                // 1769472 * 2
    __bf16* WT1   = (__bf16*)(ws + 9792512);                // 524288 * 2
    __bf16* WT2   = (__bf16*)(ws + 10841088);               // 131072 * 2

    k_trans<<<dim3(1024 / 32, 1728 / 32), 256, 0, stream>>>(W0, WT0, 1728, 1024);
    k_trans<<<dim3(512 / 32, 1024 / 32), 256, 0, stream>>>(W1, WT1, 1024, 512);
    k_trans<<<dim3(256 / 32, 512 / 32), 256, 0, stream>>>(W2, WT2, 512, 256);

    k_hash<<<(NROWS + 511) / 512, 128, 0, stream>>>(mh_tab, hw, sig);
    k_topk<<<dim3(NB, F_MH), 256, 0, stream>>>(oh_tab, hw, sig, oh_ids, mh_ids, sel);
    k_feats<<<NB, 256, 0, stream>>>(oh_tab, sp_tab, oh_ids, sp_ids, feats);
    k_attn<<<dim3(NB, F_MH, 2), 256, 0, stream>>>(oh_tab, mh_tab, oh_ids, mh_ids, sel,
                                                  sqW, sqb, skW, skb, svW, svb, soW, sob,
                                                  lqW, lqb, lkW, lkb, lvW, lvb, loW, lob,
                                                  feats);
    gemm_mfma<<<dim3(16, 8), 256, 0, stream>>>(feats, WT0, b0, x0, 512, 1024, 1728, 1);
    gemm_mfma<<<dim3(8, 8), 256, 0, stream>>>(x0, WT1, b1, x1, 512, 512, 1024, 1);
    gemm_mfma<<<dim3(4, 8), 256, 0, stream>>>(x1, WT2, b2, x2, 512, 256, 512, 1);
    k_out<<<NB / 4, 256, 0, stream>>>(x2, outW, outb, (float*)d_out);
}